// Round 4
// baseline (522.236 us; speedup 1.0000x reference)
//
#include <hip/hip_runtime.h>

#define D 128
#define NB 512   // bucket slots per domain (bucket = node >> 8)
#define BSLACK 4160   // per-bucket CSR slack: 256*16 pad + 15 align + 48 sentinels (min gap 49)
#define CHUNK 8       // consecutive nodes streamed per wave (must divide 256)

typedef __attribute__((ext_vector_type(8))) short bf16x8;
typedef __attribute__((ext_vector_type(4))) float f32x4;
typedef __attribute__((ext_vector_type(2))) float f32x2;
typedef __attribute__((ext_vector_type(4))) int i32x4;

static __device__ inline unsigned pack_bf16x2(float a, float b) {
    unsigned ua = __float_as_uint(a);
    unsigned ub = __float_as_uint(b);
    ua += 0x7fffu + ((ua >> 16) & 1u);
    ub += 0x7fffu + ((ub >> 16) & 1u);
    return (ua >> 16) | (ub & 0xffff0000u);
}

// ---- bucket histogram (LDS only) ----
__global__ __launch_bounds__(256) void bh_k(const int* __restrict__ dst_s,
                                            const int* __restrict__ dst_t,
                                            int* __restrict__ bcnt, int E) {
    int d = blockIdx.y;
    const int* dst = d ? dst_t : dst_s;
    __shared__ int h[NB];
    for (int i = threadIdx.x; i < NB; i += 256) h[i] = 0;
    __syncthreads();
    int stride = gridDim.x * 256;
    for (int e = blockIdx.x * 256 + threadIdx.x; e < E; e += stride)
        atomicAdd(&h[dst[e] >> 8], 1);
    __syncthreads();
    for (int i = threadIdx.x; i < NB; i += 256)
        if (h[i]) atomicAdd(&bcnt[d * NB + i], h[i]);
}

// ---- exclusive scan of 1024 bucket counts ----
__global__ __launch_bounds__(1024) void scanB_k(const int* __restrict__ bcnt,
                                                int* __restrict__ bbase,
                                                int* __restrict__ cursor) {
    __shared__ int sh[1024];
    int t = threadIdx.x;
    int v = bcnt[t];
    sh[t] = v;
    __syncthreads();
    for (int o = 1; o < 1024; o <<= 1) {
        int x = (t >= o) ? sh[t - o] : 0;
        __syncthreads();
        sh[t] += x;
        __syncthreads();
    }
    int ex = sh[t] - v;
    bbase[t] = ex; cursor[t] = ex;
    if (t == 1023) bbase[1024] = sh[1023];
}

// ---- bin edges into bucket regions: src | (dst&255)<<24 ----
__global__ __launch_bounds__(256) void bin_k(const int* __restrict__ src_s,
                                             const int* __restrict__ dst_s,
                                             const int* __restrict__ src_t,
                                             const int* __restrict__ dst_t,
                                             int* __restrict__ cursor,
                                             unsigned* __restrict__ pairs, int E) {
    int d = blockIdx.y;
    const int* src = d ? src_t : src_s;
    const int* dst = d ? dst_t : dst_s;
    int* cur = cursor + d * NB;
    __shared__ int h[NB];
    __shared__ int gb[NB];
    int t0 = blockIdx.x * 2048;
    if (t0 >= E) return;
    for (int i = threadIdx.x; i < NB; i += 256) h[i] = 0;
    __syncthreads();
    int rank[8]; unsigned pk[8]; short bk[8];
    #pragma unroll
    for (int j = 0; j < 8; ++j) {
        int e = t0 + j * 256 + threadIdx.x;
        if (e < E) {
            int dd = dst[e], s = src[e];
            bk[j] = (short)(dd >> 8);
            pk[j] = (unsigned)s | ((unsigned)(dd & 255) << 24);
            rank[j] = atomicAdd(&h[dd >> 8], 1);
        } else bk[j] = -1;
    }
    __syncthreads();
    for (int i = threadIdx.x; i < NB; i += 256)
        gb[i] = h[i] ? atomicAdd(&cur[i], h[i]) : 0;
    __syncthreads();
    #pragma unroll
    for (int j = 0; j < 8; ++j)
        if (bk[j] >= 0) pairs[gb[bk[j]] + rank[j]] = pk[j];
}

// ---- per-bucket: LDS node hist -> nspan/dinv, scatter into pad16 CSR ----
// bucket g's CSR region: cbase = align16(bbase[g]) + g*BSLACK
__global__ __launch_bounds__(256) void csrb_k(const unsigned* __restrict__ pairs,
                                              const int* __restrict__ bbase,
                                              int2* __restrict__ nspan,
                                              float* __restrict__ dinv,
                                              int* __restrict__ csr, int N) {
    int d = blockIdx.y, bx = blockIdx.x, t = threadIdx.x;
    int g = d * NB + bx;
    int e0 = bbase[g], e1 = bbase[g + 1];
    int cbase = ((e0 + 15) & ~15) + g * BSLACK;
    float* dv = dinv + (size_t)d * (N + 1);
    int2* ns = nspan + (size_t)d * N;
    __shared__ int lh[256];
    __shared__ int lex[256];
    __shared__ int lc[256];
    lh[t] = 0; lc[t] = 0;
    __syncthreads();
    for (int e = e0 + t; e < e1; e += 256)
        atomicAdd(&lh[pairs[e] >> 24], 1);
    __syncthreads();
    int node = (bx << 8) + t;
    bool valid = node < N;
    int deg = lh[t];
    int pdeg = valid ? (((deg + 16) >> 4) << 4) : 0;   // pad16(deg + self)
    lex[t] = pdeg;
    __syncthreads();
    for (int o = 1; o < 256; o <<= 1) {
        int x = (t >= o) ? lex[t - o] : 0;
        __syncthreads();
        lex[t] += x;
        __syncthreads();
    }
    int start = cbase + lex[t] - pdeg;
    if (valid) {
        ns[node] = make_int2(start, start + pdeg);
        dv[node] = rsqrtf((float)(deg + 1));
    }
    lex[t] = start;               // own-slot overwrite; cross-thread reads after barrier
    __syncthreads();
    for (int e = e0 + t; e < e1; e += 256) {
        unsigned p = pairs[e];
        int dn = p >> 24;
        int rank = atomicAdd(&lc[dn], 1);
        csr[lex[dn] + rank] = (int)(p & 0xffffffu);
    }
    __syncthreads();
    if (valid) {
        int b = lex[t];
        csr[b + deg] = node;                            // self (pre-scaled row IS the self term)
        for (int k = deg + 1; k < pdeg; ++k) csr[b + k] = N;   // sentinel zero-row
    }
    if (t == 255) {
        // 48 sentinels after the bucket's used region: the agg kernels'
        // 2-window-ahead gathers may use CSR values up to +47 past a
        // chunk's end (row N = zeros). Min inter-region gap is 49.
        int bend = start + pdeg;   // == bucket used end (pdeg==0 if invalid)
        for (int i = 0; i < 48; ++i) csr[bend + i] = N;
    }
    if (bx == 0 && t == 0) dv[N] = 0.f;                 // sentinel row scale
}

// ================= MFMA GEMM =================
__global__ __launch_bounds__(256) void packW_k(const float* __restrict__ W1,
                                               const float* __restrict__ W2,
                                               unsigned short* __restrict__ wp1,
                                               unsigned short* __restrict__ wp2) {
    const float* W = blockIdx.x ? W2 : W1;
    unsigned short* wp = blockIdx.x ? wp2 : wp1;
    for (int idx = threadIdx.x; idx < 2048; idx += 256) {
        int f = idx >> 6, lane = idx & 63;
        int t = f >> 2, c = f & 3;
        int q = lane >> 4, nn = lane & 15;
        #pragma unroll
        for (int j = 0; j < 8; ++j) {
            unsigned u = __float_as_uint(W[(c * 32 + q * 8 + j) * 128 + t * 16 + nn]);
            u += 0x7fffu + ((u >> 16) & 1u);
            wp[idx * 8 + j] = (unsigned short)(u >> 16);
        }
    }
}

// hbuf8 row r (fp8) = fp8( dinv[r] * (x[r] @ W) )  -- pre-scaled; row N = zeros (dinv=0)
__global__ __launch_bounds__(256) void gemm_mfma(const void* __restrict__ xs,
                                                 const void* __restrict__ xt,
                                                 const unsigned short* __restrict__ wp,
                                                 unsigned* __restrict__ hb,
                                                 const float* __restrict__ dinv,
                                                 int N, int in_bf16) {
    int d = blockIdx.y;
    const void* xin = d ? xt : xs;
    unsigned* out = hb + (size_t)d * (N + 1) * 32;
    const float* dv = dinv + (size_t)d * (N + 1);
    __shared__ float cs[64 * 132];
    int tid = threadIdx.x;
    int wave = tid >> 6, lane = tid & 63;
    int quad = lane >> 4, nn = lane & 15;
    long long blockbase = (long long)blockIdx.x * 64;
    long long ar = blockbase + wave * 16 + nn;
    if (ar > N - 1) ar = N - 1;          // inputs have N rows

    bf16x8 a[4];
    if (in_bf16) {
        const uint4* xr = (const uint4*)((const unsigned short*)xin + ar * 128);
        #pragma unroll
        for (int c = 0; c < 4; ++c) {
            union { uint4 u; bf16x8 v; } cv;
            cv.u = xr[c * 4 + quad];
            a[c] = cv.v;
        }
    } else {
        const float4* xr = (const float4*)((const float*)xin + ar * 128);
        #pragma unroll
        for (int c = 0; c < 4; ++c) {
            float4 lo = xr[c * 8 + quad * 2];
            float4 hi = xr[c * 8 + quad * 2 + 1];
            union { bf16x8 v; unsigned u[4]; } au;
            au.u[0] = pack_bf16x2(lo.x, lo.y);
            au.u[1] = pack_bf16x2(lo.z, lo.w);
            au.u[2] = pack_bf16x2(hi.x, hi.y);
            au.u[3] = pack_bf16x2(hi.z, hi.w);
            a[c] = au.v;
        }
    }

    f32x4 acc[8];
    #pragma unroll
    for (int t = 0; t < 8; ++t) acc[t] = (f32x4){0.f, 0.f, 0.f, 0.f};
    const bf16x8* wf = (const bf16x8*)wp;
    #pragma unroll
    for (int t = 0; t < 8; ++t) {
        #pragma unroll
        for (int c = 0; c < 4; ++c) {
            bf16x8 b = wf[(t * 4 + c) * 64 + lane];
            acc[t] = __builtin_amdgcn_mfma_f32_16x16x32_bf16(a[c], b, acc[t], 0, 0, 0);
        }
    }

    #pragma unroll
    for (int t = 0; t < 8; ++t) {
        #pragma unroll
        for (int r = 0; r < 4; ++r)
            cs[(wave * 16 + quad * 4 + r) * 132 + t * 16 + nn] = acc[t][r];
    }
    __syncthreads();

    #pragma unroll
    for (int i = 0; i < 8; ++i) {
        int idx = tid + i * 256;
        int r = idx >> 5, c4 = idx & 31;
        long long row = blockbase + r;
        if (row <= N) {
            float s = dv[row];
            const float4 v = *(const float4*)&cs[r * 132 + c4 * 4];
            int pk = __builtin_amdgcn_cvt_pk_fp8_f32(v.x * s, v.y * s, 0, false);
            pk = __builtin_amdgcn_cvt_pk_fp8_f32(v.z * s, v.w * s, pk, true);
            out[row * 32 + c4] = (unsigned)pk;
        }
    }
}

// ---- streaming agg, dwordx2 gathers, 2-windows-ahead pipeline ----
// Lane roles: rg = lane>>4 (row-group 0-3), fo = lane&15 (feature octet).
// A window = 16 CSR entries. Gather inst j (j=0..3) fetches rows
// csr[e+4*rg+j] : 4 rows x 128B = 512B per instruction; lane reads 8B
// (features 8*fo..8*fo+7) as uint2. Three gather buffers (A,B,C) keep
// 2 windows in flight; CSR int4 per lane at csr[e + 4*rg] (rotating 3-deep).
// XCD partition: blockIdx.x decodes so domain 0 -> XCDs 0-3, domain 1 -> 4-7.
#define NTLD(p) __builtin_nontemporal_load((const i32x4*)(p))

#define GATHER(g0, g1, g2, g3, c)                                            \
        g0 = *(const uint2*)(hsl + (((unsigned)(c).x) << 5));                \
        g1 = *(const uint2*)(hsl + (((unsigned)(c).y) << 5));                \
        g2 = *(const uint2*)(hsl + (((unsigned)(c).z) << 5));                \
        g3 = *(const uint2*)(hsl + (((unsigned)(c).w) << 5));

#define CONS1(g)                                                             \
        { f32x2 lo, hi;                                                      \
          lo = __builtin_amdgcn_cvt_pk_f32_fp8((int)(g).x, false);           \
          hi = __builtin_amdgcn_cvt_pk_f32_fp8((int)(g).x, true);            \
          s0 += lo; s1 += hi;                                                \
          lo = __builtin_amdgcn_cvt_pk_f32_fp8((int)(g).y, false);           \
          hi = __builtin_amdgcn_cvt_pk_f32_fp8((int)(g).y, true);            \
          s2 += lo; s3 += hi; }

#define BOUND                                                                \
        if (en >= end) {                                                     \
            finalize(k);                                                     \
            if (++k >= cnt) break;                                           \
            end = __shfl(myns.y, k);                                         \
            s0 = s1 = s2 = s3 = (f32x2){0.f, 0.f};                           \
        }                                                                    \
        e = en;

#define AGG_PIPE_LOOP                                                        \
    i32x4 ca = NTLD(cp + e), cb = NTLD(cp + e + 16), cc = NTLD(cp + e + 32); \
    uint2 A0, A1, A2, A3, B0, B1, B2, B3, C0, C1, C2, C3;                    \
    GATHER(A0, A1, A2, A3, ca)                                               \
    GATHER(B0, B1, B2, B3, cb)                                               \
    for (;;) {                                                               \
        int en;                                                              \
        ca = NTLD(cp + e + 48);                                              \
        GATHER(C0, C1, C2, C3, cc)                                           \
        CONS1(A0) CONS1(A1) CONS1(A2) CONS1(A3)                              \
        en = e + 16; BOUND                                                   \
        cb = NTLD(cp + e + 48);                                              \
        GATHER(A0, A1, A2, A3, ca)                                           \
        CONS1(B0) CONS1(B1) CONS1(B2) CONS1(B3)                              \
        en = e + 16; BOUND                                                   \
        cc = NTLD(cp + e + 48);                                              \
        GATHER(B0, B1, B2, B3, cb)                                           \
        CONS1(C0) CONS1(C1) CONS1(C2) CONS1(C3)                              \
        en = e + 16; BOUND                                                   \
    }

// ---- agg layer 1: sum of pre-scaled fp8 rows over pad16 list; bf16+relu out ----
__global__ __launch_bounds__(256) void agg1_k(const unsigned* __restrict__ hb,
                                              const float* __restrict__ dinv,
                                              const int2* __restrict__ nspan,
                                              const int* __restrict__ csr,
                                              const float* __restrict__ b1,
                                              const float* __restrict__ b1t,
                                              uint4* __restrict__ abuf,
                                              int N, int nblk) {
    int lin = blockIdx.x;
    int xcd = lin & 7;
    int d = xcd >> 2;
    int blkd = ((lin >> 3) << 2) + (xcd & 3);
    int wave = threadIdx.x >> 6, lane = threadIdx.x & 63;
    int node0 = (blkd * 4 + wave) * CHUNK;
    if (node0 >= N) return;
    const unsigned* hs = hb + (size_t)d * (N + 1) * 32;
    const float* dv = dinv + (size_t)d * (N + 1);
    const int2* ns = nspan + (size_t)d * N;
    uint4* out = abuf + (size_t)d * N * 16;
    const float* bias = d ? b1t : b1;
    int cnt = min(CHUNK, N - node0);
    int rg = lane >> 4, fo = lane & 15;
    int lc = lane & (CHUNK - 1);
    int2 myns = make_int2(0, 0);
    float mydv = 0.f;
    if (lc < cnt) { myns = ns[node0 + lc]; mydv = dv[node0 + lc]; }
    float4 bA = ((const float4*)bias)[2 * fo];
    float4 bB = ((const float4*)bias)[2 * fo + 1];
    const unsigned* hsl = hs + (fo << 1);
    const int* cp = csr + (rg << 2);

    f32x2 s0 = (f32x2){0.f, 0.f}, s1 = s0, s2 = s0, s3 = s0;

    auto finalize = [&](int kk) {
        float a[8] = {s0[0], s0[1], s1[0], s1[1], s2[0], s2[1], s3[0], s3[1]};
        #pragma unroll
        for (int i = 0; i < 8; ++i) {
            a[i] += __shfl_xor(a[i], 16);
            a[i] += __shfl_xor(a[i], 32);
        }
        float dik = __shfl(mydv, kk);
        float o0 = fmaxf(fmaf(dik, a[0], bA.x), 0.f);
        float o1 = fmaxf(fmaf(dik, a[1], bA.y), 0.f);
        float o2 = fmaxf(fmaf(dik, a[2], bA.z), 0.f);
        float o3 = fmaxf(fmaf(dik, a[3], bA.w), 0.f);
        float o4 = fmaxf(fmaf(dik, a[4], bB.x), 0.f);
        float o5 = fmaxf(fmaf(dik, a[5], bB.y), 0.f);
        float o6 = fmaxf(fmaf(dik, a[6], bB.z), 0.f);
        float o7 = fmaxf(fmaf(dik, a[7], bB.w), 0.f);
        if (lane < 16)
            out[(size_t)(node0 + kk) * 16 + fo] =
                make_uint4(pack_bf16x2(o0, o1), pack_bf16x2(o2, o3),
                           pack_bf16x2(o4, o5), pack_bf16x2(o6, o7));
    };

    int k = 0;
    int e = __shfl(myns.x, 0);
    int end = __shfl(myns.y, 0);
    AGG_PIPE_LOOP
}

// ---- agg layer 2 fused with per-node loss dots ----
__global__ __launch_bounds__(256) void agg2_k(const unsigned* __restrict__ hb,
                                              const float* __restrict__ dinv,
                                              const int2* __restrict__ nspan,
                                              const int* __restrict__ csr,
                                              const float* __restrict__ b2,
                                              const float* __restrict__ b2t,
                                              const float* __restrict__ clsW,
                                              const float* __restrict__ duW,
                                              const float* __restrict__ diW,
                                              const int* __restrict__ nus,
                                              const int* __restrict__ nut,
                                              float2* __restrict__ nodeDots,
                                              int N, int nblk) {
    int lin = blockIdx.x;
    int xcd = lin & 7;
    int d = xcd >> 2;
    int blkd = ((lin >> 3) << 2) + (xcd & 3);
    int wave = threadIdx.x >> 6, lane = threadIdx.x & 63;
    int node0 = (blkd * 4 + wave) * CHUNK;
    if (node0 >= N) return;
    const unsigned* hs = hb + (size_t)d * (N + 1) * 32;
    const float* dv = dinv + (size_t)d * (N + 1);
    const int2* ns = nspan + (size_t)d * N;
    float2* nd = nodeDots + (size_t)d * N;
    const float* bias = d ? b2t : b2;
    int nu = d ? nut[0] : nus[0];
    int cnt = min(CHUNK, N - node0);
    int rg = lane >> 4, fo = lane & 15;
    int lc = lane & (CHUNK - 1);
    int2 myns = make_int2(0, 0);
    float mydv = 0.f;
    if (lc < cnt) { myns = ns[node0 + lc]; mydv = dv[node0 + lc]; }
    float4 bA = ((const float4*)bias)[2 * fo];
    float4 bB = ((const float4*)bias)[2 * fo + 1];
    const unsigned* hsl = hs + (fo << 1);
    const int* cp = csr + (rg << 2);

    f32x2 s0 = (f32x2){0.f, 0.f}, s1 = s0, s2 = s0, s3 = s0;

    auto finalize = [&](int kk) {
        float a[8] = {s0[0], s0[1], s1[0], s1[1], s2[0], s2[1], s3[0], s3[1]};
        #pragma unroll
        for (int i = 0; i < 8; ++i) {
            a[i] += __shfl_xor(a[i], 16);
            a[i] += __shfl_xor(a[i], 32);
        }
        float dik = __shfl(mydv, kk);
        float o0 = fmaf(dik, a[0], bA.x);
        float o1 = fmaf(dik, a[1], bA.y);
        float o2 = fmaf(dik, a[2], bA.z);
        float o3 = fmaf(dik, a[3], bA.w);
        float o4 = fmaf(dik, a[4], bB.x);
        float o5 = fmaf(dik, a[5], bB.y);
        float o6 = fmaf(dik, a[6], bB.z);
        float o7 = fmaf(dik, a[7], bB.w);
        int nodek = node0 + kk;
        int sel = (nodek >= nu) ? 1 : 0;
        const float4* cw = (const float4*)clsW;
        float4 wa0 = cw[sel * 32 + 2 * fo];
        float4 wa1 = cw[sel * 32 + 2 * fo + 1];
        const float4* bw = (const float4*)(sel ? diW : duW);
        float4 wb0 = bw[2 * fo];
        float4 wb1 = bw[2 * fo + 1];
        float p = o0 * wa0.x + o1 * wa0.y + o2 * wa0.z + o3 * wa0.w +
                  o4 * wa1.x + o5 * wa1.y + o6 * wa1.z + o7 * wa1.w;
        float q = o0 * wb0.x + o1 * wb0.y + o2 * wb0.z + o3 * wb0.w +
                  o4 * wb1.x + o5 * wb1.y + o6 * wb1.z + o7 * wb1.w;
        #pragma unroll
        for (int o = 8; o > 0; o >>= 1) {
            p += __shfl_xor(p, o);
            q += __shfl_xor(q, o);
        }
        if (lane == 0) nd[nodek] = make_float2(p, q);
    };

    int k = 0;
    int e = __shfl(myns.x, 0);
    int end = __shfl(myns.y, 0);
    AGG_PIPE_LOOP
}

// ---- pair loss ----
__global__ __launch_bounds__(256) void loss_k(const float2* __restrict__ nodeDots,
                                              const int* __restrict__ us, const int* __restrict__ is_,
                                              const int* __restrict__ ls,
                                              const int* __restrict__ ut, const int* __restrict__ it,
                                              const int* __restrict__ lt,
                                              const float* __restrict__ clsb,
                                              const float* __restrict__ dub,
                                              const float* __restrict__ dib,
                                              const int* __restrict__ nus,
                                              const int* __restrict__ nut,
                                              float* __restrict__ accum, int Bn, int N) {
    int d = blockIdx.y;
    const float2* nd = nodeDots + (size_t)d * N;
    const int* users = d ? ut : us;
    const int* items = d ? it : is_;
    const int* labels = d ? lt : ls;
    int nu = d ? nut[0] : nus[0];
    float* acc = accum + 3 * d;
    int k = blockIdx.x * 256 + threadIdx.x;
    float bce = 0.f, cu = 0.f, ci = 0.f;
    if (k < Bn) {
        int u = users[k];
        int t = items[k] + nu;
        float2 ud = nd[u];
        float2 id = nd[t];
        float z = ud.x + id.x + clsb[0];
        float y = (float)labels[k];
        float sp = fmaxf(z, 0.f) + log1pf(expf(-fabsf(z)));
        bce = sp - y * z;
        cu = 1.f / (1.f + expf(-(ud.y + dub[0])));
        ci = 1.f / (1.f + expf(-(id.y + dib[0])));
    }
    #pragma unroll
    for (int o = 32; o > 0; o >>= 1) {
        bce += __shfl_xor(bce, o);
        cu += __shfl_xor(cu, o);
        ci += __shfl_xor(ci, o);
    }
    __shared__ float sh[12];
    int lane = threadIdx.x & 63, wave = threadIdx.x >> 6;
    if (lane == 0) { sh[wave * 3 + 0] = bce; sh[wave * 3 + 1] = cu; sh[wave * 3 + 2] = ci; }
    __syncthreads();
    if (threadIdx.x < 3) {
        float v = sh[threadIdx.x] + sh[3 + threadIdx.x] + sh[6 + threadIdx.x] + sh[9 + threadIdx.x];
        atomicAdd(&acc[threadIdx.x], v);
    }
}

__global__ void finalize_k(const float* __restrict__ accum, float* __restrict__ out, float invB) {
    if (threadIdx.x == 0 && blockIdx.x == 0) {
        float clf = (accum[0] + accum[3]) * invB;
        float dom = fabsf((accum[1] - accum[4]) * invB) + fabsf((accum[2] - accum[5]) * invB);
        out[0] = clf + dom;
    }
}

extern "C" void kernel_launch(void* const* d_in, const int* in_sizes, int n_in,
                              void* d_out, int out_size, void* d_ws, size_t ws_size,
                              hipStream_t stream) {
    const float* feats_s = (const float*)d_in[0];
    const float* feats_t = (const float*)d_in[1];
    const float* W1   = (const float*)d_in[2];
    const float* b1   = (const float*)d_in[3];
    const float* W2   = (const float*)d_in[4];
    const float* b2   = (const float*)d_in[5];
    const float* clsW = (const float*)d_in[6];
    const float* clsb = (const float*)d_in[7];
    const float* duW  = (const float*)d_in[8];
    const float* dub  = (const float*)d_in[9];
    const float* diW  = (const float*)d_in[10];
    const float* dib  = (const float*)d_in[11];

    int N = in_sizes[0] / D;
    int E = in_sizes[12];
    int B = in_sizes[16];
    int nb = (N + 255) >> 8;          // real buckets per domain (<= NB)

    char* ws = (char*)d_ws;
    size_t off = 0;
    auto alloc = [&](size_t bytes) -> void* {
        void* p = ws + off;
        off += (bytes + 255) & ~(size_t)255;
        return p;
    };
    int*      bcnt   = (int*)  alloc(2 * NB * 4);
    int*      bbase  = (int*)  alloc((2 * NB + 1) * 4);
    int*      cursor = (int*)  alloc(2 * NB * 4);
    float*    dinv   = (float*)alloc((size_t)2 * (N + 1) * 4);
    int2*     nspan  = (int2*) alloc((size_t)2 * N * 8);
    unsigned* pairs  = (unsigned*)alloc((size_t)2 * E * 4);
    int*      csr    = (int*)  alloc(((size_t)2 * E + 2 * NB * BSLACK + 256) * 4);
    unsigned* hbuf8  = (unsigned*)alloc((size_t)2 * (N + 1) * 128);   // fp8 pre-scaled rows
    unsigned* abuf   = (unsigned*)alloc((size_t)2 * N * 256);         // bf16 agg1 rows
    float2*   nodeDots = (float2*)alloc((size_t)2 * N * 8);
    unsigned short* wp1 = (unsigned short*)alloc(16384 * 2);
    unsigned short* wp2 = (unsigned short*)alloc(16384 * 2);
    float*    accum  = (float*)alloc(128);

    hipMemsetAsync(accum, 0, 6 * sizeof(float), stream);
    hipMemsetAsync(bcnt, 0, 2 * NB * 4, stream);

    const int* esrc_s = (const int*)d_in[12];
    const int* edst_s = (const int*)d_in[13];
    const int* esrc_t = (const int*)d_in[14];
    const int* edst_t = (const int*)d_in[15];
    const int* user_s = (const int*)d_in[16];
    const int* item_s = (const int*)d_in[17];
    const int* lab_s  = (const int*)d_in[18];
    const int* user_t = (const int*)d_in[19];
    const int* item_t = (const int*)d_in[20];
    const int* lab_t  = (const int*)d_in[21];
    const int* nup_s  = (const int*)d_in[22];
    const int* nup_t  = (const int*)d_in[23];

    packW_k<<<2, 256, 0, stream>>>(W1, W2, wp1, wp2);

    bh_k<<<dim3(512, 2), 256, 0, stream>>>(edst_s, edst_t, bcnt, E);
    scanB_k<<<1, 1024, 0, stream>>>(bcnt, bbase, cursor);
    bin_k<<<dim3((E + 2047) / 2048, 2), 256, 0, stream>>>(esrc_s, edst_s, esrc_t, edst_t,
                                                          cursor, pairs, E);
    csrb_k<<<dim3(nb, 2), 256, 0, stream>>>(pairs, bbase, nspan, dinv, csr, N);

    int ngb = (N + 64) / 64;   // covers rows 0..N (incl. sentinel row N)
    int nchunk = (N + CHUNK - 1) / CHUNK;
    int nblk = (nchunk + 3) / 4;            // blocks per domain
    int gx = 8 * ((nblk + 3) / 4);          // XCD-partitioned grid (both domains)
    gemm_mfma<<<dim3(ngb, 2), 256, 0, stream>>>(feats_s, feats_t, wp1, hbuf8, dinv, N, 0);
    agg1_k<<<gx, 256, 0, stream>>>(hbuf8, dinv, nspan, csr, b1, b1,
                                   (uint4*)abuf, N, nblk);
    gemm_mfma<<<dim3(ngb, 2), 256, 0, stream>>>(abuf, abuf + (size_t)N * 64, wp2,
                                                hbuf8, dinv, N, 1);
    agg2_k<<<gx, 256, 0, stream>>>(hbuf8, dinv, nspan, csr, b2, b2,
                                   clsW, duW, diW, nup_s, nup_t,
                                   nodeDots, N, nblk);
    loss_k<<<dim3((B + 255) / 256, 2), 256, 0, stream>>>(nodeDots,
                                                         user_s, item_s, lab_s,
                                                         user_t, item_t, lab_t,
                                                         clsb, dub, dib, nup_s, nup_t,
                                                         accum, B, N);
    finalize_k<<<1, 64, 0, stream>>>(accum, (float*)d_out, 1.0f / (float)B);
}

// Round 5
// 516.518 us; speedup vs baseline: 1.0111x; 1.0111x over previous
//
#include <hip/hip_runtime.h>

#define D 128
#define NB 512   // bucket slots per domain (bucket = node >> 8)
#define BSLACK 4160   // per-bucket CSR slack: 256*16 pad + 15 align + 48 sentinels (min gap 49)
#define CHUNK 8       // consecutive nodes streamed per wave (must divide 256)

typedef __attribute__((ext_vector_type(8))) short bf16x8;
typedef __attribute__((ext_vector_type(4))) float f32x4;
typedef __attribute__((ext_vector_type(2))) float f32x2;
typedef __attribute__((ext_vector_type(4))) int i32x4;

static __device__ inline unsigned pack_bf16x2(float a, float b) {
    unsigned ua = __float_as_uint(a);
    unsigned ub = __float_as_uint(b);
    ua += 0x7fffu + ((ua >> 16) & 1u);
    ub += 0x7fffu + ((ub >> 16) & 1u);
    return (ua >> 16) | (ub & 0xffff0000u);
}

// ---- bucket histogram (LDS only) ----
__global__ __launch_bounds__(256) void bh_k(const int* __restrict__ dst_s,
                                            const int* __restrict__ dst_t,
                                            int* __restrict__ bcnt, int E) {
    int d = blockIdx.y;
    const int* dst = d ? dst_t : dst_s;
    __shared__ int h[NB];
    for (int i = threadIdx.x; i < NB; i += 256) h[i] = 0;
    __syncthreads();
    int stride = gridDim.x * 256;
    for (int e = blockIdx.x * 256 + threadIdx.x; e < E; e += stride)
        atomicAdd(&h[dst[e] >> 8], 1);
    __syncthreads();
    for (int i = threadIdx.x; i < NB; i += 256)
        if (h[i]) atomicAdd(&bcnt[d * NB + i], h[i]);
}

// ---- exclusive scan of 1024 bucket counts ----
__global__ __launch_bounds__(1024) void scanB_k(const int* __restrict__ bcnt,
                                                int* __restrict__ bbase,
                                                int* __restrict__ cursor) {
    __shared__ int sh[1024];
    int t = threadIdx.x;
    int v = bcnt[t];
    sh[t] = v;
    __syncthreads();
    for (int o = 1; o < 1024; o <<= 1) {
        int x = (t >= o) ? sh[t - o] : 0;
        __syncthreads();
        sh[t] += x;
        __syncthreads();
    }
    int ex = sh[t] - v;
    bbase[t] = ex; cursor[t] = ex;
    if (t == 1023) bbase[1024] = sh[1023];
}

// ---- bin edges into bucket regions: src | (dst&255)<<24 ----
__global__ __launch_bounds__(256) void bin_k(const int* __restrict__ src_s,
                                             const int* __restrict__ dst_s,
                                             const int* __restrict__ src_t,
                                             const int* __restrict__ dst_t,
                                             int* __restrict__ cursor,
                                             unsigned* __restrict__ pairs, int E) {
    int d = blockIdx.y;
    const int* src = d ? src_t : src_s;
    const int* dst = d ? dst_t : dst_s;
    int* cur = cursor + d * NB;
    __shared__ int h[NB];
    __shared__ int gb[NB];
    int t0 = blockIdx.x * 2048;
    if (t0 >= E) return;
    for (int i = threadIdx.x; i < NB; i += 256) h[i] = 0;
    __syncthreads();
    int rank[8]; unsigned pk[8]; short bk[8];
    #pragma unroll
    for (int j = 0; j < 8; ++j) {
        int e = t0 + j * 256 + threadIdx.x;
        if (e < E) {
            int dd = dst[e], s = src[e];
            bk[j] = (short)(dd >> 8);
            pk[j] = (unsigned)s | ((unsigned)(dd & 255) << 24);
            rank[j] = atomicAdd(&h[dd >> 8], 1);
        } else bk[j] = -1;
    }
    __syncthreads();
    for (int i = threadIdx.x; i < NB; i += 256)
        gb[i] = h[i] ? atomicAdd(&cur[i], h[i]) : 0;
    __syncthreads();
    #pragma unroll
    for (int j = 0; j < 8; ++j)
        if (bk[j] >= 0) pairs[gb[bk[j]] + rank[j]] = pk[j];
}

// ---- per-bucket: LDS node hist -> nspan/dinv, scatter into pad16 CSR ----
// bucket g's CSR region: cbase = align16(bbase[g]) + g*BSLACK
__global__ __launch_bounds__(256) void csrb_k(const unsigned* __restrict__ pairs,
                                              const int* __restrict__ bbase,
                                              int2* __restrict__ nspan,
                                              float* __restrict__ dinv,
                                              int* __restrict__ csr, int N) {
    int d = blockIdx.y, bx = blockIdx.x, t = threadIdx.x;
    int g = d * NB + bx;
    int e0 = bbase[g], e1 = bbase[g + 1];
    int cbase = ((e0 + 15) & ~15) + g * BSLACK;
    float* dv = dinv + (size_t)d * (N + 1);
    int2* ns = nspan + (size_t)d * N;
    __shared__ int lh[256];
    __shared__ int lex[256];
    __shared__ int lc[256];
    lh[t] = 0; lc[t] = 0;
    __syncthreads();
    for (int e = e0 + t; e < e1; e += 256)
        atomicAdd(&lh[pairs[e] >> 24], 1);
    __syncthreads();
    int node = (bx << 8) + t;
    bool valid = node < N;
    int deg = lh[t];
    int pdeg = valid ? (((deg + 16) >> 4) << 4) : 0;   // pad16(deg + self)
    lex[t] = pdeg;
    __syncthreads();
    for (int o = 1; o < 256; o <<= 1) {
        int x = (t >= o) ? lex[t - o] : 0;
        __syncthreads();
        lex[t] += x;
        __syncthreads();
    }
    int start = cbase + lex[t] - pdeg;
    if (valid) {
        ns[node] = make_int2(start, start + pdeg);
        dv[node] = rsqrtf((float)(deg + 1));
    }
    lex[t] = start;               // own-slot overwrite; cross-thread reads after barrier
    __syncthreads();
    for (int e = e0 + t; e < e1; e += 256) {
        unsigned p = pairs[e];
        int dn = p >> 24;
        int rank = atomicAdd(&lc[dn], 1);
        csr[lex[dn] + rank] = (int)(p & 0xffffffu);
    }
    __syncthreads();
    if (valid) {
        int b = lex[t];
        csr[b + deg] = node;                            // self (pre-scaled row IS the self term)
        for (int k = deg + 1; k < pdeg; ++k) csr[b + k] = N;   // sentinel zero-row
    }
    if (t == 255) {
        // 48 sentinels after the bucket's used region: the agg kernels'
        // 2-window-ahead pipeline touches CSR values up to +47 past a
        // chunk's end (row N = zeros). Min inter-region gap is 49.
        int bend = start + pdeg;   // == bucket used end (pdeg==0 if invalid)
        for (int i = 0; i < 48; ++i) csr[bend + i] = N;
    }
    if (bx == 0 && t == 0) dv[N] = 0.f;                 // sentinel row scale
}

// ================= MFMA GEMM =================
__global__ __launch_bounds__(256) void packW_k(const float* __restrict__ W1,
                                               const float* __restrict__ W2,
                                               unsigned short* __restrict__ wp1,
                                               unsigned short* __restrict__ wp2) {
    const float* W = blockIdx.x ? W2 : W1;
    unsigned short* wp = blockIdx.x ? wp2 : wp1;
    for (int idx = threadIdx.x; idx < 2048; idx += 256) {
        int f = idx >> 6, lane = idx & 63;
        int t = f >> 2, c = f & 3;
        int q = lane >> 4, nn = lane & 15;
        #pragma unroll
        for (int j = 0; j < 8; ++j) {
            unsigned u = __float_as_uint(W[(c * 32 + q * 8 + j) * 128 + t * 16 + nn]);
            u += 0x7fffu + ((u >> 16) & 1u);
            wp[idx * 8 + j] = (unsigned short)(u >> 16);
        }
    }
}

// hbuf8 row r (fp8) = fp8( dinv[r] * (x[r] @ W) )  -- pre-scaled; row N = zeros (dinv=0)
__global__ __launch_bounds__(256) void gemm_mfma(const void* __restrict__ xs,
                                                 const void* __restrict__ xt,
                                                 const unsigned short* __restrict__ wp,
                                                 unsigned* __restrict__ hb,
                                                 const float* __restrict__ dinv,
                                                 int N, int in_bf16) {
    int d = blockIdx.y;
    const void* xin = d ? xt : xs;
    unsigned* out = hb + (size_t)d * (N + 1) * 32;
    const float* dv = dinv + (size_t)d * (N + 1);
    __shared__ float cs[64 * 132];
    int tid = threadIdx.x;
    int wave = tid >> 6, lane = tid & 63;
    int quad = lane >> 4, nn = lane & 15;
    long long blockbase = (long long)blockIdx.x * 64;
    long long ar = blockbase + wave * 16 + nn;
    if (ar > N - 1) ar = N - 1;          // inputs have N rows

    bf16x8 a[4];
    if (in_bf16) {
        const uint4* xr = (const uint4*)((const unsigned short*)xin + ar * 128);
        #pragma unroll
        for (int c = 0; c < 4; ++c) {
            union { uint4 u; bf16x8 v; } cv;
            cv.u = xr[c * 4 + quad];
            a[c] = cv.v;
        }
    } else {
        const float4* xr = (const float4*)((const float*)xin + ar * 128);
        #pragma unroll
        for (int c = 0; c < 4; ++c) {
            float4 lo = xr[c * 8 + quad * 2];
            float4 hi = xr[c * 8 + quad * 2 + 1];
            union { bf16x8 v; unsigned u[4]; } au;
            au.u[0] = pack_bf16x2(lo.x, lo.y);
            au.u[1] = pack_bf16x2(lo.z, lo.w);
            au.u[2] = pack_bf16x2(hi.x, hi.y);
            au.u[3] = pack_bf16x2(hi.z, hi.w);
            a[c] = au.v;
        }
    }

    f32x4 acc[8];
    #pragma unroll
    for (int t = 0; t < 8; ++t) acc[t] = (f32x4){0.f, 0.f, 0.f, 0.f};
    const bf16x8* wf = (const bf16x8*)wp;
    #pragma unroll
    for (int t = 0; t < 8; ++t) {
        #pragma unroll
        for (int c = 0; c < 4; ++c) {
            bf16x8 b = wf[(t * 4 + c) * 64 + lane];
            acc[t] = __builtin_amdgcn_mfma_f32_16x16x32_bf16(a[c], b, acc[t], 0, 0, 0);
        }
    }

    #pragma unroll
    for (int t = 0; t < 8; ++t) {
        #pragma unroll
        for (int r = 0; r < 4; ++r)
            cs[(wave * 16 + quad * 4 + r) * 132 + t * 16 + nn] = acc[t][r];
    }
    __syncthreads();

    #pragma unroll
    for (int i = 0; i < 8; ++i) {
        int idx = tid + i * 256;
        int r = idx >> 5, c4 = idx & 31;
        long long row = blockbase + r;
        if (row <= N) {
            float s = dv[row];
            const float4 v = *(const float4*)&cs[r * 132 + c4 * 4];
            int pk = __builtin_amdgcn_cvt_pk_fp8_f32(v.x * s, v.y * s, 0, false);
            pk = __builtin_amdgcn_cvt_pk_fp8_f32(v.z * s, v.w * s, pk, true);
            out[row * 32 + c4] = (unsigned)pk;
        }
    }
}

// ---- streaming agg (R3 lane layout): one wave owns CHUNK consecutive nodes.
// half = lane>>5 handles 8 of each window's 16 edges; lane li owns feature
// dword li of every edge in its half (2-segment coalesced gathers).
// TWO windows in flight via 3 rotating 8-dword gather buffers (uA/uB/uC);
// CSR int4 pairs rotate 3-deep. Accumulation order identical to R3.
#define NTLD(p) __builtin_nontemporal_load((const i32x4*)(p))

#define AGG_GATHER(u, q0, q1)                                                \
        u[0] = hsl[((unsigned)(q0).x) << 5];                                 \
        u[1] = hsl[((unsigned)(q0).y) << 5];                                 \
        u[2] = hsl[((unsigned)(q0).z) << 5];                                 \
        u[3] = hsl[((unsigned)(q0).w) << 5];                                 \
        u[4] = hsl[((unsigned)(q1).x) << 5];                                 \
        u[5] = hsl[((unsigned)(q1).y) << 5];                                 \
        u[6] = hsl[((unsigned)(q1).z) << 5];                                 \
        u[7] = hsl[((unsigned)(q1).w) << 5];

#define AGG_CONSUME(u)                                                       \
        { f32x2 lo, hi;                                                      \
          lo = __builtin_amdgcn_cvt_pk_f32_fp8((int)u[0], false);            \
          hi = __builtin_amdgcn_cvt_pk_f32_fp8((int)u[0], true);             \
          s01 += lo; s23 += hi;                                              \
          lo = __builtin_amdgcn_cvt_pk_f32_fp8((int)u[1], false);            \
          hi = __builtin_amdgcn_cvt_pk_f32_fp8((int)u[1], true);             \
          s01 += lo; s23 += hi;                                              \
          lo = __builtin_amdgcn_cvt_pk_f32_fp8((int)u[2], false);            \
          hi = __builtin_amdgcn_cvt_pk_f32_fp8((int)u[2], true);             \
          s01 += lo; s23 += hi;                                              \
          lo = __builtin_amdgcn_cvt_pk_f32_fp8((int)u[3], false);            \
          hi = __builtin_amdgcn_cvt_pk_f32_fp8((int)u[3], true);             \
          s01 += lo; s23 += hi;                                              \
          lo = __builtin_amdgcn_cvt_pk_f32_fp8((int)u[4], false);            \
          hi = __builtin_amdgcn_cvt_pk_f32_fp8((int)u[4], true);             \
          s01 += lo; s23 += hi;                                              \
          lo = __builtin_amdgcn_cvt_pk_f32_fp8((int)u[5], false);            \
          hi = __builtin_amdgcn_cvt_pk_f32_fp8((int)u[5], true);             \
          s01 += lo; s23 += hi;                                              \
          lo = __builtin_amdgcn_cvt_pk_f32_fp8((int)u[6], false);            \
          hi = __builtin_amdgcn_cvt_pk_f32_fp8((int)u[6], true);             \
          s01 += lo; s23 += hi;                                              \
          lo = __builtin_amdgcn_cvt_pk_f32_fp8((int)u[7], false);            \
          hi = __builtin_amdgcn_cvt_pk_f32_fp8((int)u[7], true);             \
          s01 += lo; s23 += hi; }

#define BOUND                                                                \
        if (en >= end) {                                                     \
            finalize(k);                                                     \
            if (++k >= cnt) break;                                           \
            end = __shfl(myns.y, k);                                         \
            s01 = (f32x2){0.f, 0.f};                                         \
            s23 = (f32x2){0.f, 0.f};                                         \
        }                                                                    \
        e = en;

#define AGG_PIPE_LOOP                                                        \
    i32x4 a0 = NTLD(cp + e), a1 = NTLD(cp + e + 4);                          \
    i32x4 b0 = NTLD(cp + e + 16), b1 = NTLD(cp + e + 20);                    \
    i32x4 t0 = NTLD(cp + e + 32), t1 = NTLD(cp + e + 36);                    \
    unsigned uA[8], uB[8], uC[8];                                            \
    AGG_GATHER(uA, a0, a1)                                                   \
    AGG_GATHER(uB, b0, b1)                                                   \
    for (;;) {                                                               \
        int en = e + 16;                                                     \
        AGG_GATHER(uC, t0, t1)                                               \
        a0 = NTLD(cp + e + 48); a1 = NTLD(cp + e + 52);                      \
        AGG_CONSUME(uA)                                                      \
        BOUND                                                                \
        en = e + 16;                                                         \
        AGG_GATHER(uA, a0, a1)                                               \
        b0 = NTLD(cp + e + 48); b1 = NTLD(cp + e + 52);                      \
        AGG_CONSUME(uB)                                                      \
        BOUND                                                                \
        en = e + 16;                                                         \
        AGG_GATHER(uB, b0, b1)                                               \
        t0 = NTLD(cp + e + 48); t1 = NTLD(cp + e + 52);                      \
        AGG_CONSUME(uC)                                                      \
        BOUND                                                                \
    }

// ---- agg layer 1: sum of pre-scaled fp8 rows over pad16 list; bf16+relu out ----
__global__ __launch_bounds__(256, 4) void agg1_k(const unsigned* __restrict__ hb,
                                                 const float* __restrict__ dinv,
                                                 const int2* __restrict__ nspan,
                                                 const int* __restrict__ csr,
                                                 const float* __restrict__ bias,
                                                 uint2* __restrict__ out, int N) {
    int d = blockIdx.y;
    const unsigned* hs = hb + (size_t)d * (N + 1) * 32;
    const float* dv = dinv + (size_t)d * (N + 1);
    const int2* ns = nspan + (size_t)d * N;
    uint2* outp = out + (size_t)d * N * 32;
    int wave = threadIdx.x >> 6, lane = threadIdx.x & 63;
    int node0 = (blockIdx.x * 4 + wave) * CHUNK;
    if (node0 >= N) return;
    int cnt = min(CHUNK, N - node0);
    int half = lane >> 5, li = lane & 31;
    int lc = lane & (CHUNK - 1);
    int2 myns = make_int2(0, 0);
    float mydv = 0.f;
    if (lc < cnt) { myns = ns[node0 + lc]; mydv = dv[node0 + lc]; }
    float4 b4 = ((const float4*)bias)[li];
    const unsigned* hsl = hs + li;
    const int* cp = csr + 8 * half;

    f32x2 s01 = (f32x2){0.f, 0.f};
    f32x2 s23 = (f32x2){0.f, 0.f};

    auto finalize = [&](int kk) {
        float a0 = s01[0], a1 = s01[1], a2 = s23[0], a3 = s23[1];
        a0 += __shfl_xor(a0, 32);
        a1 += __shfl_xor(a1, 32);
        a2 += __shfl_xor(a2, 32);
        a3 += __shfl_xor(a3, 32);
        float dik = __shfl(mydv, kk);
        float o0 = fmaxf(fmaf(dik, a0, b4.x), 0.f);
        float o1 = fmaxf(fmaf(dik, a1, b4.y), 0.f);
        float o2 = fmaxf(fmaf(dik, a2, b4.z), 0.f);
        float o3 = fmaxf(fmaf(dik, a3, b4.w), 0.f);
        if (half == 0)
            outp[(size_t)(node0 + kk) * 32 + li] =
                make_uint2(pack_bf16x2(o0, o1), pack_bf16x2(o2, o3));
    };

    int k = 0;
    int e = __shfl(myns.x, 0);
    int end = __shfl(myns.y, 0);
    AGG_PIPE_LOOP
}

// ---- agg layer 2 fused with per-node loss dots ----
__global__ __launch_bounds__(256, 4) void agg2_k(const unsigned* __restrict__ hb,
                                                 const float* __restrict__ dinv,
                                                 const int2* __restrict__ nspan,
                                                 const int* __restrict__ csr,
                                                 const float* __restrict__ bias,
                                                 const float* __restrict__ clsW,
                                                 const float* __restrict__ duW,
                                                 const float* __restrict__ diW,
                                                 const int* __restrict__ nus,
                                                 const int* __restrict__ nut,
                                                 float2* __restrict__ nodeDots, int N) {
    int d = blockIdx.y;
    const unsigned* hs = hb + (size_t)d * (N + 1) * 32;
    const float* dv = dinv + (size_t)d * (N + 1);
    const int2* ns = nspan + (size_t)d * N;
    float2* nd = nodeDots + (size_t)d * N;
    int nu = d ? nut[0] : nus[0];
    int wave = threadIdx.x >> 6, lane = threadIdx.x & 63;
    int node0 = (blockIdx.x * 4 + wave) * CHUNK;
    if (node0 >= N) return;
    int cnt = min(CHUNK, N - node0);
    int half = lane >> 5, li = lane & 31;
    int lc = lane & (CHUNK - 1);
    int2 myns = make_int2(0, 0);
    float mydv = 0.f;
    if (lc < cnt) { myns = ns[node0 + lc]; mydv = dv[node0 + lc]; }
    float4 b4 = ((const float4*)bias)[li];
    float4 wA0 = ((const float4*)clsW)[li];
    float4 wA1 = ((const float4*)clsW)[32 + li];
    float4 wB0 = ((const float4*)duW)[li];
    float4 wB1 = ((const float4*)diW)[li];
    const unsigned* hsl = hs + li;
    const int* cp = csr + 8 * half;

    f32x2 s01 = (f32x2){0.f, 0.f};
    f32x2 s23 = (f32x2){0.f, 0.f};

    auto finalize = [&](int kk) {
        float a0 = s01[0], a1 = s01[1], a2 = s23[0], a3 = s23[1];
        a0 += __shfl_xor(a0, 32);
        a1 += __shfl_xor(a1, 32);
        a2 += __shfl_xor(a2, 32);
        a3 += __shfl_xor(a3, 32);
        float dik = __shfl(mydv, kk);
        float o0 = fmaf(dik, a0, b4.x);
        float o1 = fmaf(dik, a1, b4.y);
        float o2 = fmaf(dik, a2, b4.z);
        float o3 = fmaf(dik, a3, b4.w);
        int nodek = node0 + kk;
        int sel = (nodek >= nu) ? 1 : 0;
        float4 wA = sel ? wA1 : wA0;
        float4 wB = sel ? wB1 : wB0;
        float p = o0 * wA.x + o1 * wA.y + o2 * wA.z + o3 * wA.w;
        float q = o0 * wB.x + o1 * wB.y + o2 * wB.z + o3 * wB.w;
        #pragma unroll
        for (int o = 16; o > 0; o >>= 1) {
            p += __shfl_xor(p, o);
            q += __shfl_xor(q, o);
        }
        if (lane == 0) nd[nodek] = make_float2(p, q);
    };

    int k = 0;
    int e = __shfl(myns.x, 0);
    int end = __shfl(myns.y, 0);
    AGG_PIPE_LOOP
}

// ---- pair loss ----
__global__ __launch_bounds__(256) void loss_k(const float2* __restrict__ nodeDots,
                                              const int* __restrict__ us, const int* __restrict__ is_,
                                              const int* __restrict__ ls,
                                              const int* __restrict__ ut, const int* __restrict__ it,
                                              const int* __restrict__ lt,
                                              const float* __restrict__ clsb,
                                              const float* __restrict__ dub,
                                              const float* __restrict__ dib,
                                              const int* __restrict__ nus,
                                              const int* __restrict__ nut,
                                              float* __restrict__ accum, int Bn, int N) {
    int d = blockIdx.y;
    const float2* nd = nodeDots + (size_t)d * N;
    const int* users = d ? ut : us;
    const int* items = d ? it : is_;
    const int* labels = d ? lt : ls;
    int nu = d ? nut[0] : nus[0];
    float* acc = accum + 3 * d;
    int k = blockIdx.x * 256 + threadIdx.x;
    float bce = 0.f, cu = 0.f, ci = 0.f;
    if (k < Bn) {
        int u = users[k];
        int t = items[k] + nu;
        float2 ud = nd[u];
        float2 id = nd[t];
        float z = ud.x + id.x + clsb[0];
        float y = (float)labels[k];
        float sp = fmaxf(z, 0.f) + log1pf(expf(-fabsf(z)));
        bce = sp - y * z;
        cu = 1.f / (1.f + expf(-(ud.y + dub[0])));
        ci = 1.f / (1.f + expf(-(id.y + dib[0])));
    }
    #pragma unroll
    for (int o = 32; o > 0; o >>= 1) {
        bce += __shfl_xor(bce, o);
        cu += __shfl_xor(cu, o);
        ci += __shfl_xor(ci, o);
    }
    __shared__ float sh[12];
    int lane = threadIdx.x & 63, wave = threadIdx.x >> 6;
    if (lane == 0) { sh[wave * 3 + 0] = bce; sh[wave * 3 + 1] = cu; sh[wave * 3 + 2] = ci; }
    __syncthreads();
    if (threadIdx.x < 3) {
        float v = sh[threadIdx.x] + sh[3 + threadIdx.x] + sh[6 + threadIdx.x] + sh[9 + threadIdx.x];
        atomicAdd(&acc[threadIdx.x], v);
    }
}

__global__ void finalize_k(const float* __restrict__ accum, float* __restrict__ out, float invB) {
    if (threadIdx.x == 0 && blockIdx.x == 0) {
        float clf = (accum[0] + accum[3]) * invB;
        float dom = fabsf((accum[1] - accum[4]) * invB) + fabsf((accum[2] - accum[5]) * invB);
        out[0] = clf + dom;
    }
}

extern "C" void kernel_launch(void* const* d_in, const int* in_sizes, int n_in,
                              void* d_out, int out_size, void* d_ws, size_t ws_size,
                              hipStream_t stream) {
    const float* feats_s = (const float*)d_in[0];
    const float* feats_t = (const float*)d_in[1];
    const float* W1   = (const float*)d_in[2];
    const float* b1   = (const float*)d_in[3];
    const float* W2   = (const float*)d_in[4];
    const float* b2   = (const float*)d_in[5];
    const float* clsW = (const float*)d_in[6];
    const float* clsb = (const float*)d_in[7];
    const float* duW  = (const float*)d_in[8];
    const float* dub  = (const float*)d_in[9];
    const float* diW  = (const float*)d_in[10];
    const float* dib  = (const float*)d_in[11];

    int N = in_sizes[0] / D;
    int E = in_sizes[12];
    int B = in_sizes[16];
    int nb = (N + 255) >> 8;          // real buckets per domain (<= NB)

    char* ws = (char*)d_ws;
    size_t off = 0;
    auto alloc = [&](size_t bytes) -> void* {
        void* p = ws + off;
        off += (bytes + 255) & ~(size_t)255;
        return p;
    };
    int*      bcnt   = (int*)  alloc(2 * NB * 4);
    int*      bbase  = (int*)  alloc((2 * NB + 1) * 4);
    int*      cursor = (int*)  alloc(2 * NB * 4);
    float*    dinv   = (float*)alloc((size_t)2 * (N + 1) * 4);
    int2*     nspan  = (int2*) alloc((size_t)2 * N * 8);
    unsigned* pairs  = (unsigned*)alloc((size_t)2 * E * 4);
    int*      csr    = (int*)  alloc(((size_t)2 * E + 2 * NB * BSLACK + 256) * 4);
    unsigned* hbuf8  = (unsigned*)alloc((size_t)2 * (N + 1) * 128);   // fp8 pre-scaled rows
    unsigned* abuf   = (unsigned*)alloc((size_t)2 * N * 256);         // bf16 agg1 rows
    float2*   nodeDots = (float2*)alloc((size_t)2 * N * 8);
    unsigned short* wp1 = (unsigned short*)alloc(16384 * 2);
    unsigned short* wp2 = (unsigned short*)alloc(16384 * 2);
    float*    accum  = (float*)alloc(128);

    hipMemsetAsync(accum, 0, 6 * sizeof(float), stream);
    hipMemsetAsync(bcnt, 0, 2 * NB * 4, stream);

    const int* esrc_s = (const int*)d_in[12];
    const int* edst_s = (const int*)d_in[13];
    const int* esrc_t = (const int*)d_in[14];
    const int* edst_t = (const int*)d_in[15];
    const int* user_s = (const int*)d_in[16];
    const int* item_s = (const int*)d_in[17];
    const int* lab_s  = (const int*)d_in[18];
    const int* user_t = (const int*)d_in[19];
    const int* item_t = (const int*)d_in[20];
    const int* lab_t  = (const int*)d_in[21];
    const int* nup_s  = (const int*)d_in[22];
    const int* nup_t  = (const int*)d_in[23];

    packW_k<<<2, 256, 0, stream>>>(W1, W2, wp1, wp2);

    bh_k<<<dim3(64, 2), 256, 0, stream>>>(edst_s, edst_t, bcnt, E);
    scanB_k<<<1, 1024, 0, stream>>>(bcnt, bbase, cursor);
    bin_k<<<dim3((E + 2047) / 2048, 2), 256, 0, stream>>>(esrc_s, edst_s, esrc_t, edst_t,
                                                          cursor, pairs, E);
    csrb_k<<<dim3(nb, 2), 256, 0, stream>>>(pairs, bbase, nspan, dinv, csr, N);

    int ngb = (N + 64) / 64;   // covers rows 0..N (incl. sentinel row N)
    int nchunk = (N + CHUNK - 1) / CHUNK;
    gemm_mfma<<<dim3(ngb, 2), 256, 0, stream>>>(feats_s, feats_t, wp1, hbuf8, dinv, N, 0);
    agg1_k<<<dim3((nchunk + 3) / 4, 2), 256, 0, stream>>>(hbuf8, dinv, nspan, csr, b1,
                                                          (uint2*)abuf, N);
    gemm_mfma<<<dim3(ngb, 2), 256, 0, stream>>>(abuf, abuf + (size_t)N * 64, wp2,
                                                hbuf8, dinv, N, 1);
    agg2_k<<<dim3((nchunk + 3) / 4, 2), 256, 0, stream>>>(hbuf8, dinv, nspan, csr, b2,
                                                          clsW, duW, diW, nup_s, nup_t,
                                                          nodeDots, N);
    loss_k<<<dim3((B + 255) / 256, 2), 256, 0, stream>>>(nodeDots,
                                                         user_s, item_s, lab_s,
                                                         user_t, item_t, lab_t,
                                                         clsb, dub, dib, nup_s, nup_t,
                                                         accum, B, N);
    finalize_k<<<1, 64, 0, stream>>>(accum, (float*)d_out, 1.0f / (float)B);
}

// Round 6
// 490.705 us; speedup vs baseline: 1.0643x; 1.0526x over previous
//
#include <hip/hip_runtime.h>

#define D 128
#define NB 512   // bucket slots per domain (bucket = node >> 8)
#define BSLACK 4160   // per-bucket CSR slack: 256*16 pad + 15 align + 48 sentinels (min gap 49)
#define CHUNK 8       // consecutive nodes streamed per wave (must divide 256)

typedef __attribute__((ext_vector_type(8))) short bf16x8;
typedef __attribute__((ext_vector_type(4))) float f32x4;
typedef __attribute__((ext_vector_type(2))) float f32x2;
typedef __attribute__((ext_vector_type(4))) int i32x4;

static __device__ inline unsigned pack_bf16x2(float a, float b) {
    unsigned ua = __float_as_uint(a);
    unsigned ub = __float_as_uint(b);
    ua += 0x7fffu + ((ua >> 16) & 1u);
    ub += 0x7fffu + ((ub >> 16) & 1u);
    return (ua >> 16) | (ub & 0xffff0000u);
}

// ---- bucket histogram (LDS only) ----
__global__ __launch_bounds__(256) void bh_k(const int* __restrict__ dst_s,
                                            const int* __restrict__ dst_t,
                                            int* __restrict__ bcnt, int E) {
    int d = blockIdx.y;
    const int* dst = d ? dst_t : dst_s;
    __shared__ int h[NB];
    for (int i = threadIdx.x; i < NB; i += 256) h[i] = 0;
    __syncthreads();
    int stride = gridDim.x * 256;
    for (int e = blockIdx.x * 256 + threadIdx.x; e < E; e += stride)
        atomicAdd(&h[dst[e] >> 8], 1);
    __syncthreads();
    for (int i = threadIdx.x; i < NB; i += 256)
        if (h[i]) atomicAdd(&bcnt[d * NB + i], h[i]);
}

// ---- exclusive scan of 1024 bucket counts ----
__global__ __launch_bounds__(1024) void scanB_k(const int* __restrict__ bcnt,
                                                int* __restrict__ bbase,
                                                int* __restrict__ cursor) {
    __shared__ int sh[1024];
    int t = threadIdx.x;
    int v = bcnt[t];
    sh[t] = v;
    __syncthreads();
    for (int o = 1; o < 1024; o <<= 1) {
        int x = (t >= o) ? sh[t - o] : 0;
        __syncthreads();
        sh[t] += x;
        __syncthreads();
    }
    int ex = sh[t] - v;
    bbase[t] = ex; cursor[t] = ex;
    if (t == 1023) bbase[1024] = sh[1023];
}

// ---- bin edges into bucket regions: src | (dst&255)<<24 ----
__global__ __launch_bounds__(256) void bin_k(const int* __restrict__ src_s,
                                             const int* __restrict__ dst_s,
                                             const int* __restrict__ src_t,
                                             const int* __restrict__ dst_t,
                                             int* __restrict__ cursor,
                                             unsigned* __restrict__ pairs, int E) {
    int d = blockIdx.y;
    const int* src = d ? src_t : src_s;
    const int* dst = d ? dst_t : dst_s;
    int* cur = cursor + d * NB;
    __shared__ int h[NB];
    __shared__ int gb[NB];
    int t0 = blockIdx.x * 2048;
    if (t0 >= E) return;
    for (int i = threadIdx.x; i < NB; i += 256) h[i] = 0;
    __syncthreads();
    int rank[8]; unsigned pk[8]; short bk[8];
    #pragma unroll
    for (int j = 0; j < 8; ++j) {
        int e = t0 + j * 256 + threadIdx.x;
        if (e < E) {
            int dd = dst[e], s = src[e];
            bk[j] = (short)(dd >> 8);
            pk[j] = (unsigned)s | ((unsigned)(dd & 255) << 24);
            rank[j] = atomicAdd(&h[dd >> 8], 1);
        } else bk[j] = -1;
    }
    __syncthreads();
    for (int i = threadIdx.x; i < NB; i += 256)
        gb[i] = h[i] ? atomicAdd(&cur[i], h[i]) : 0;
    __syncthreads();
    #pragma unroll
    for (int j = 0; j < 8; ++j)
        if (bk[j] >= 0) pairs[gb[bk[j]] + rank[j]] = pk[j];
}

// ---- per-bucket: LDS node hist -> nspan/dinv, scatter into pad16 CSR ----
// bucket g's CSR region: cbase = align16(bbase[g]) + g*BSLACK
__global__ __launch_bounds__(256) void csrb_k(const unsigned* __restrict__ pairs,
                                              const int* __restrict__ bbase,
                                              int2* __restrict__ nspan,
                                              float* __restrict__ dinv,
                                              int* __restrict__ csr, int N) {
    int d = blockIdx.y, bx = blockIdx.x, t = threadIdx.x;
    int g = d * NB + bx;
    int e0 = bbase[g], e1 = bbase[g + 1];
    int cbase = ((e0 + 15) & ~15) + g * BSLACK;
    float* dv = dinv + (size_t)d * (N + 1);
    int2* ns = nspan + (size_t)d * N;
    __shared__ int lh[256];
    __shared__ int lex[256];
    __shared__ int lc[256];
    lh[t] = 0; lc[t] = 0;
    __syncthreads();
    for (int e = e0 + t; e < e1; e += 256)
        atomicAdd(&lh[pairs[e] >> 24], 1);
    __syncthreads();
    int node = (bx << 8) + t;
    bool valid = node < N;
    int deg = lh[t];
    int pdeg = valid ? (((deg + 16) >> 4) << 4) : 0;   // pad16(deg + self)
    lex[t] = pdeg;
    __syncthreads();
    for (int o = 1; o < 256; o <<= 1) {
        int x = (t >= o) ? lex[t - o] : 0;
        __syncthreads();
        lex[t] += x;
        __syncthreads();
    }
    int start = cbase + lex[t] - pdeg;
    if (valid) {
        ns[node] = make_int2(start, start + pdeg);
        dv[node] = rsqrtf((float)(deg + 1));
    }
    lex[t] = start;               // own-slot overwrite; cross-thread reads after barrier
    __syncthreads();
    for (int e = e0 + t; e < e1; e += 256) {
        unsigned p = pairs[e];
        int dn = p >> 24;
        int rank = atomicAdd(&lc[dn], 1);
        csr[lex[dn] + rank] = (int)(p & 0xffffffu);
    }
    __syncthreads();
    if (valid) {
        int b = lex[t];
        csr[b + deg] = node;                            // self (pre-scaled row IS the self term)
        for (int k = deg + 1; k < pdeg; ++k) csr[b + k] = N;   // sentinel zero-row
    }
    if (t == 255) {
        // 48 sentinels after the bucket's used region: the agg kernels'
        // 2-window-ahead pipeline touches CSR values up to +47 past a
        // chunk's end (row N = zeros). Min inter-region gap is 49.
        int bend = start + pdeg;   // == bucket used end (pdeg==0 if invalid)
        for (int i = 0; i < 48; ++i) csr[bend + i] = N;
    }
    if (bx == 0 && t == 0) dv[N] = 0.f;                 // sentinel row scale
}

// ================= MFMA GEMM =================
__global__ __launch_bounds__(256) void packW_k(const float* __restrict__ W1,
                                               const float* __restrict__ W2,
                                               unsigned short* __restrict__ wp1,
                                               unsigned short* __restrict__ wp2) {
    const float* W = blockIdx.x ? W2 : W1;
    unsigned short* wp = blockIdx.x ? wp2 : wp1;
    for (int idx = threadIdx.x; idx < 2048; idx += 256) {
        int f = idx >> 6, lane = idx & 63;
        int t = f >> 2, c = f & 3;
        int q = lane >> 4, nn = lane & 15;
        #pragma unroll
        for (int j = 0; j < 8; ++j) {
            unsigned u = __float_as_uint(W[(c * 32 + q * 8 + j) * 128 + t * 16 + nn]);
            u += 0x7fffu + ((u >> 16) & 1u);
            wp[idx * 8 + j] = (unsigned short)(u >> 16);
        }
    }
}

// hbuf8 row r (fp8) = fp8( dinv[r] * (x[r] @ W) )  -- pre-scaled; row N = zeros (dinv=0)
__global__ __launch_bounds__(256) void gemm_mfma(const void* __restrict__ xs,
                                                 const void* __restrict__ xt,
                                                 const unsigned short* __restrict__ wp,
                                                 unsigned* __restrict__ hb,
                                                 const float* __restrict__ dinv,
                                                 int N, int in_bf16) {
    int d = blockIdx.y;
    const void* xin = d ? xt : xs;
    unsigned* out = hb + (size_t)d * (N + 1) * 32;
    const float* dv = dinv + (size_t)d * (N + 1);
    __shared__ float cs[64 * 132];
    int tid = threadIdx.x;
    int wave = tid >> 6, lane = tid & 63;
    int quad = lane >> 4, nn = lane & 15;
    long long blockbase = (long long)blockIdx.x * 64;
    long long ar = blockbase + wave * 16 + nn;
    if (ar > N - 1) ar = N - 1;          // inputs have N rows

    bf16x8 a[4];
    if (in_bf16) {
        const uint4* xr = (const uint4*)((const unsigned short*)xin + ar * 128);
        #pragma unroll
        for (int c = 0; c < 4; ++c) {
            union { uint4 u; bf16x8 v; } cv;
            cv.u = xr[c * 4 + quad];
            a[c] = cv.v;
        }
    } else {
        const float4* xr = (const float4*)((const float*)xin + ar * 128);
        #pragma unroll
        for (int c = 0; c < 4; ++c) {
            float4 lo = xr[c * 8 + quad * 2];
            float4 hi = xr[c * 8 + quad * 2 + 1];
            union { bf16x8 v; unsigned u[4]; } au;
            au.u[0] = pack_bf16x2(lo.x, lo.y);
            au.u[1] = pack_bf16x2(lo.z, lo.w);
            au.u[2] = pack_bf16x2(hi.x, hi.y);
            au.u[3] = pack_bf16x2(hi.z, hi.w);
            a[c] = au.v;
        }
    }

    f32x4 acc[8];
    #pragma unroll
    for (int t = 0; t < 8; ++t) acc[t] = (f32x4){0.f, 0.f, 0.f, 0.f};
    const bf16x8* wf = (const bf16x8*)wp;
    #pragma unroll
    for (int t = 0; t < 8; ++t) {
        #pragma unroll
        for (int c = 0; c < 4; ++c) {
            bf16x8 b = wf[(t * 4 + c) * 64 + lane];
            acc[t] = __builtin_amdgcn_mfma_f32_16x16x32_bf16(a[c], b, acc[t], 0, 0, 0);
        }
    }

    #pragma unroll
    for (int t = 0; t < 8; ++t) {
        #pragma unroll
        for (int r = 0; r < 4; ++r)
            cs[(wave * 16 + quad * 4 + r) * 132 + t * 16 + nn] = acc[t][r];
    }
    __syncthreads();

    #pragma unroll
    for (int i = 0; i < 8; ++i) {
        int idx = tid + i * 256;
        int r = idx >> 5, c4 = idx & 31;
        long long row = blockbase + r;
        if (row <= N) {
            float s = dv[row];
            const float4 v = *(const float4*)&cs[r * 132 + c4 * 4];
            int pk = __builtin_amdgcn_cvt_pk_fp8_f32(v.x * s, v.y * s, 0, false);
            pk = __builtin_amdgcn_cvt_pk_fp8_f32(v.z * s, v.w * s, pk, true);
            out[row * 32 + c4] = (unsigned)pk;
        }
    }
}

// ---- streaming agg (R3 lane layout): one wave owns CHUNK consecutive nodes.
// half = lane>>5 handles 8 of each window's 16 edges; lane li owns feature
// dword li of every edge in its half (2-segment coalesced gathers).
// TWO windows in flight via 3 rotating 8-dword gather buffers (uA/uB/uC).
// sched_barrier(0) between gather-issue and consume pins the issue order so
// the compiler cannot sink loads to their use (R4/R5 failure mode: VGPR
// stayed ~44-48 = pipeline collapsed). With pinned order the auto-inserted
// waitcnt before consume is a counted vmcnt (never 0 mid-stream).
#define NTLD(p) __builtin_nontemporal_load((const i32x4*)(p))
#define SBAR __builtin_amdgcn_sched_barrier(0);

#define AGG_GATHER(u, q0, q1)                                                \
        u[0] = hsl[((unsigned)(q0).x) << 5];                                 \
        u[1] = hsl[((unsigned)(q0).y) << 5];                                 \
        u[2] = hsl[((unsigned)(q0).z) << 5];                                 \
        u[3] = hsl[((unsigned)(q0).w) << 5];                                 \
        u[4] = hsl[((unsigned)(q1).x) << 5];                                 \
        u[5] = hsl[((unsigned)(q1).y) << 5];                                 \
        u[6] = hsl[((unsigned)(q1).z) << 5];                                 \
        u[7] = hsl[((unsigned)(q1).w) << 5];

#define AGG_CONSUME(u)                                                       \
        { f32x2 lo, hi;                                                      \
          lo = __builtin_amdgcn_cvt_pk_f32_fp8((int)u[0], false);            \
          hi = __builtin_amdgcn_cvt_pk_f32_fp8((int)u[0], true);             \
          s01 += lo; s23 += hi;                                              \
          lo = __builtin_amdgcn_cvt_pk_f32_fp8((int)u[1], false);            \
          hi = __builtin_amdgcn_cvt_pk_f32_fp8((int)u[1], true);             \
          s01 += lo; s23 += hi;                                              \
          lo = __builtin_amdgcn_cvt_pk_f32_fp8((int)u[2], false);            \
          hi = __builtin_amdgcn_cvt_pk_f32_fp8((int)u[2], true);             \
          s01 += lo; s23 += hi;                                              \
          lo = __builtin_amdgcn_cvt_pk_f32_fp8((int)u[3], false);            \
          hi = __builtin_amdgcn_cvt_pk_f32_fp8((int)u[3], true);             \
          s01 += lo; s23 += hi;                                              \
          lo = __builtin_amdgcn_cvt_pk_f32_fp8((int)u[4], false);            \
          hi = __builtin_amdgcn_cvt_pk_f32_fp8((int)u[4], true);             \
          s01 += lo; s23 += hi;                                              \
          lo = __builtin_amdgcn_cvt_pk_f32_fp8((int)u[5], false);            \
          hi = __builtin_amdgcn_cvt_pk_f32_fp8((int)u[5], true);             \
          s01 += lo; s23 += hi;                                              \
          lo = __builtin_amdgcn_cvt_pk_f32_fp8((int)u[6], false);            \
          hi = __builtin_amdgcn_cvt_pk_f32_fp8((int)u[6], true);             \
          s01 += lo; s23 += hi;                                              \
          lo = __builtin_amdgcn_cvt_pk_f32_fp8((int)u[7], false);            \
          hi = __builtin_amdgcn_cvt_pk_f32_fp8((int)u[7], true);             \
          s01 += lo; s23 += hi; }

#define BOUND                                                                \
        if (en >= end) {                                                     \
            finalize(k);                                                     \
            if (++k >= cnt) break;                                           \
            end = __shfl(myns.y, k);                                         \
            s01 = (f32x2){0.f, 0.f};                                         \
            s23 = (f32x2){0.f, 0.f};                                         \
        }                                                                    \
        e = en;

#define AGG_PIPE_LOOP                                                        \
    i32x4 a0 = NTLD(cp + e), a1 = NTLD(cp + e + 4);                          \
    i32x4 b0 = NTLD(cp + e + 16), b1 = NTLD(cp + e + 20);                    \
    i32x4 t0 = NTLD(cp + e + 32), t1 = NTLD(cp + e + 36);                    \
    unsigned uA[8], uB[8], uC[8];                                            \
    AGG_GATHER(uA, a0, a1)                                                   \
    AGG_GATHER(uB, b0, b1)                                                   \
    SBAR                                                                     \
    for (;;) {                                                               \
        int en = e + 16;                                                     \
        AGG_GATHER(uC, t0, t1)                                               \
        a0 = NTLD(cp + e + 48); a1 = NTLD(cp + e + 52);                      \
        SBAR                                                                 \
        AGG_CONSUME(uA)                                                      \
        BOUND                                                                \
        en = e + 16;                                                         \
        AGG_GATHER(uA, a0, a1)                                               \
        b0 = NTLD(cp + e + 48); b1 = NTLD(cp + e + 52);                      \
        SBAR                                                                 \
        AGG_CONSUME(uB)                                                      \
        BOUND                                                                \
        en = e + 16;                                                         \
        AGG_GATHER(uB, b0, b1)                                               \
        t0 = NTLD(cp + e + 48); t1 = NTLD(cp + e + 52);                      \
        SBAR                                                                 \
        AGG_CONSUME(uC)                                                      \
        BOUND                                                                \
    }

// ---- agg layer 1: sum of pre-scaled fp8 rows over pad16 list; bf16+relu out ----
__global__ __launch_bounds__(256, 4) void agg1_k(const unsigned* __restrict__ hb,
                                                 const float* __restrict__ dinv,
                                                 const int2* __restrict__ nspan,
                                                 const int* __restrict__ csr,
                                                 const float* __restrict__ bias,
                                                 uint2* __restrict__ out, int N) {
    int d = blockIdx.y;
    const unsigned* hs = hb + (size_t)d * (N + 1) * 32;
    const float* dv = dinv + (size_t)d * (N + 1);
    const int2* ns = nspan + (size_t)d * N;
    uint2* outp = out + (size_t)d * N * 32;
    int wave = threadIdx.x >> 6, lane = threadIdx.x & 63;
    int node0 = (blockIdx.x * 4 + wave) * CHUNK;
    if (node0 >= N) return;
    int cnt = min(CHUNK, N - node0);
    int half = lane >> 5, li = lane & 31;
    int lc = lane & (CHUNK - 1);
    int2 myns = make_int2(0, 0);
    float mydv = 0.f;
    if (lc < cnt) { myns = ns[node0 + lc]; mydv = dv[node0 + lc]; }
    float4 b4 = ((const float4*)bias)[li];
    const unsigned* hsl = hs + li;
    const int* cp = csr + 8 * half;

    f32x2 s01 = (f32x2){0.f, 0.f};
    f32x2 s23 = (f32x2){0.f, 0.f};

    auto finalize = [&](int kk) {
        float a0f = s01[0], a1f = s01[1], a2f = s23[0], a3f = s23[1];
        a0f += __shfl_xor(a0f, 32);
        a1f += __shfl_xor(a1f, 32);
        a2f += __shfl_xor(a2f, 32);
        a3f += __shfl_xor(a3f, 32);
        float dik = __shfl(mydv, kk);
        float o0 = fmaxf(fmaf(dik, a0f, b4.x), 0.f);
        float o1 = fmaxf(fmaf(dik, a1f, b4.y), 0.f);
        float o2 = fmaxf(fmaf(dik, a2f, b4.z), 0.f);
        float o3 = fmaxf(fmaf(dik, a3f, b4.w), 0.f);
        if (half == 0)
            outp[(size_t)(node0 + kk) * 32 + li] =
                make_uint2(pack_bf16x2(o0, o1), pack_bf16x2(o2, o3));
    };

    int k = 0;
    int e = __shfl(myns.x, 0);
    int end = __shfl(myns.y, 0);
    AGG_PIPE_LOOP
}

// ---- agg layer 2 fused with per-node loss dots ----
__global__ __launch_bounds__(256, 4) void agg2_k(const unsigned* __restrict__ hb,
                                                 const float* __restrict__ dinv,
                                                 const int2* __restrict__ nspan,
                                                 const int* __restrict__ csr,
                                                 const float* __restrict__ bias,
                                                 const float* __restrict__ clsW,
                                                 const float* __restrict__ duW,
                                                 const float* __restrict__ diW,
                                                 const int* __restrict__ nus,
                                                 const int* __restrict__ nut,
                                                 float2* __restrict__ nodeDots, int N) {
    int d = blockIdx.y;
    const unsigned* hs = hb + (size_t)d * (N + 1) * 32;
    const float* dv = dinv + (size_t)d * (N + 1);
    const int2* ns = nspan + (size_t)d * N;
    float2* nd = nodeDots + (size_t)d * N;
    int nu = d ? nut[0] : nus[0];
    int wave = threadIdx.x >> 6, lane = threadIdx.x & 63;
    int node0 = (blockIdx.x * 4 + wave) * CHUNK;
    if (node0 >= N) return;
    int cnt = min(CHUNK, N - node0);
    int half = lane >> 5, li = lane & 31;
    int lc = lane & (CHUNK - 1);
    int2 myns = make_int2(0, 0);
    float mydv = 0.f;
    if (lc < cnt) { myns = ns[node0 + lc]; mydv = dv[node0 + lc]; }
    float4 b4 = ((const float4*)bias)[li];
    float4 wA0 = ((const float4*)clsW)[li];
    float4 wA1 = ((const float4*)clsW)[32 + li];
    float4 wB0 = ((const float4*)duW)[li];
    float4 wB1 = ((const float4*)diW)[li];
    const unsigned* hsl = hs + li;
    const int* cp = csr + 8 * half;

    f32x2 s01 = (f32x2){0.f, 0.f};
    f32x2 s23 = (f32x2){0.f, 0.f};

    auto finalize = [&](int kk) {
        float a0f = s01[0], a1f = s01[1], a2f = s23[0], a3f = s23[1];
        a0f += __shfl_xor(a0f, 32);
        a1f += __shfl_xor(a1f, 32);
        a2f += __shfl_xor(a2f, 32);
        a3f += __shfl_xor(a3f, 32);
        float dik = __shfl(mydv, kk);
        float o0 = fmaf(dik, a0f, b4.x);
        float o1 = fmaf(dik, a1f, b4.y);
        float o2 = fmaf(dik, a2f, b4.z);
        float o3 = fmaf(dik, a3f, b4.w);
        int nodek = node0 + kk;
        int sel = (nodek >= nu) ? 1 : 0;
        float4 wA = sel ? wA1 : wA0;
        float4 wB = sel ? wB1 : wB0;
        float p = o0 * wA.x + o1 * wA.y + o2 * wA.z + o3 * wA.w;
        float q = o0 * wB.x + o1 * wB.y + o2 * wB.z + o3 * wB.w;
        #pragma unroll
        for (int o = 16; o > 0; o >>= 1) {
            p += __shfl_xor(p, o);
            q += __shfl_xor(q, o);
        }
        if (lane == 0) nd[nodek] = make_float2(p, q);
    };

    int k = 0;
    int e = __shfl(myns.x, 0);
    int end = __shfl(myns.y, 0);
    AGG_PIPE_LOOP
}

// ---- pair loss ----
__global__ __launch_bounds__(256) void loss_k(const float2* __restrict__ nodeDots,
                                              const int* __restrict__ us, const int* __restrict__ is_,
                                              const int* __restrict__ ls,
                                              const int* __restrict__ ut, const int* __restrict__ it,
                                              const int* __restrict__ lt,
                                              const float* __restrict__ clsb,
                                              const float* __restrict__ dub,
                                              const float* __restrict__ dib,
                                              const int* __restrict__ nus,
                                              const int* __restrict__ nut,
                                              float* __restrict__ accum, int Bn, int N) {
    int d = blockIdx.y;
    const float2* nd = nodeDots + (size_t)d * N;
    const int* users = d ? ut : us;
    const int* items = d ? it : is_;
    const int* labels = d ? lt : ls;
    int nu = d ? nut[0] : nus[0];
    float* acc = accum + 3 * d;
    int k = blockIdx.x * 256 + threadIdx.x;
    float bce = 0.f, cu = 0.f, ci = 0.f;
    if (k < Bn) {
        int u = users[k];
        int t = items[k] + nu;
        float2 ud = nd[u];
        float2 id = nd[t];
        float z = ud.x + id.x + clsb[0];
        float y = (float)labels[k];
        float sp = fmaxf(z, 0.f) + log1pf(expf(-fabsf(z)));
        bce = sp - y * z;
        cu = 1.f / (1.f + expf(-(ud.y + dub[0])));
        ci = 1.f / (1.f + expf(-(id.y + dib[0])));
    }
    #pragma unroll
    for (int o = 32; o > 0; o >>= 1) {
        bce += __shfl_xor(bce, o);
        cu += __shfl_xor(cu, o);
        ci += __shfl_xor(ci, o);
    }
    __shared__ float sh[12];
    int lane = threadIdx.x & 63, wave = threadIdx.x >> 6;
    if (lane == 0) { sh[wave * 3 + 0] = bce; sh[wave * 3 + 1] = cu; sh[wave * 3 + 2] = ci; }
    __syncthreads();
    if (threadIdx.x < 3) {
        float v = sh[threadIdx.x] + sh[3 + threadIdx.x] + sh[6 + threadIdx.x] + sh[9 + threadIdx.x];
        atomicAdd(&acc[threadIdx.x], v);
    }
}

__global__ void finalize_k(const float* __restrict__ accum, float* __restrict__ out, float invB) {
    if (threadIdx.x == 0 && blockIdx.x == 0) {
        float clf = (accum[0] + accum[3]) * invB;
        float dom = fabsf((accum[1] - accum[4]) * invB) + fabsf((accum[2] - accum[5]) * invB);
        out[0] = clf + dom;
    }
}

extern "C" void kernel_launch(void* const* d_in, const int* in_sizes, int n_in,
                              void* d_out, int out_size, void* d_ws, size_t ws_size,
                              hipStream_t stream) {
    const float* feats_s = (const float*)d_in[0];
    const float* feats_t = (const float*)d_in[1];
    const float* W1   = (const float*)d_in[2];
    const float* b1   = (const float*)d_in[3];
    const float* W2   = (const float*)d_in[4];
    const float* b2   = (const float*)d_in[5];
    const float* clsW = (const float*)d_in[6];
    const float* clsb = (const float*)d_in[7];
    const float* duW  = (const float*)d_in[8];
    const float* dub  = (const float*)d_in[9];
    const float* diW  = (const float*)d_in[10];
    const float* dib  = (const float*)d_in[11];

    int N = in_sizes[0] / D;
    int E = in_sizes[12];
    int B = in_sizes[16];
    int nb = (N + 255) >> 8;          // real buckets per domain (<= NB)

    char* ws = (char*)d_ws;
    size_t off = 0;
    auto alloc = [&](size_t bytes) -> void* {
        void* p = ws + off;
        off += (bytes + 255) & ~(size_t)255;
        return p;
    };
    int*      bcnt   = (int*)  alloc(2 * NB * 4);
    int*      bbase  = (int*)  alloc((2 * NB + 1) * 4);
    int*      cursor = (int*)  alloc(2 * NB * 4);
    float*    dinv   = (float*)alloc((size_t)2 * (N + 1) * 4);
    int2*     nspan  = (int2*) alloc((size_t)2 * N * 8);
    unsigned* pairs  = (unsigned*)alloc((size_t)2 * E * 4);
    int*      csr    = (int*)  alloc(((size_t)2 * E + 2 * NB * BSLACK + 256) * 4);
    unsigned* hbuf8  = (unsigned*)alloc((size_t)2 * (N + 1) * 128);   // fp8 pre-scaled rows
    unsigned* abuf   = (unsigned*)alloc((size_t)2 * N * 256);         // bf16 agg1 rows
    float2*   nodeDots = (float2*)alloc((size_t)2 * N * 8);
    unsigned short* wp1 = (unsigned short*)alloc(16384 * 2);
    unsigned short* wp2 = (unsigned short*)alloc(16384 * 2);
    float*    accum  = (float*)alloc(128);

    hipMemsetAsync(accum, 0, 6 * sizeof(float), stream);
    hipMemsetAsync(bcnt, 0, 2 * NB * 4, stream);

    const int* esrc_s = (const int*)d_in[12];
    const int* edst_s = (const int*)d_in[13];
    const int* esrc_t = (const int*)d_in[14];
    const int* edst_t = (const int*)d_in[15];
    const int* user_s = (const int*)d_in[16];
    const int* item_s = (const int*)d_in[17];
    const int* lab_s  = (const int*)d_in[18];
    const int* user_t = (const int*)d_in[19];
    const int* item_t = (const int*)d_in[20];
    const int* lab_t  = (const int*)d_in[21];
    const int* nup_s  = (const int*)d_in[22];
    const int* nup_t  = (const int*)d_in[23];

    packW_k<<<2, 256, 0, stream>>>(W1, W2, wp1, wp2);

    bh_k<<<dim3(512, 2), 256, 0, stream>>>(edst_s, edst_t, bcnt, E);
    scanB_k<<<1, 1024, 0, stream>>>(bcnt, bbase, cursor);
    bin_k<<<dim3((E + 2047) / 2048, 2), 256, 0, stream>>>(esrc_s, edst_s, esrc_t, edst_t,
                                                          cursor, pairs, E);
    csrb_k<<<dim3(nb, 2), 256, 0, stream>>>(pairs, bbase, nspan, dinv, csr, N);

    int ngb = (N + 64) / 64;   // covers rows 0..N (incl. sentinel row N)
    int nchunk = (N + CHUNK - 1) / CHUNK;
    gemm_mfma<<<dim3(ngb, 2), 256, 0, stream>>>(feats_s, feats_t, wp1, hbuf8, dinv, N, 0);
    agg1_k<<<dim3((nchunk + 3) / 4, 2), 256, 0, stream>>>(hbuf8, dinv, nspan, csr, b1,
                                                          (uint2*)abuf, N);
    gemm_mfma<<<dim3(ngb, 2), 256, 0, stream>>>(abuf, abuf + (size_t)N * 64, wp2,
                                                hbuf8, dinv, N, 1);
    agg2_k<<<dim3((nchunk + 3) / 4, 2), 256, 0, stream>>>(hbuf8, dinv, nspan, csr, b2,
                                                          clsW, duW, diW, nup_s, nup_t,
                                                          nodeDots, N);
    loss_k<<<dim3((B + 255) / 256, 2), 256, 0, stream>>>(nodeDots,
                                                         user_s, item_s, lab_s,
                                                         user_t, item_t, lab_t,
                                                         clsb, dub, dib, nup_s, nup_t,
                                                         accum, B, N);
    finalize_k<<<1, 64, 0, stream>>>(accum, (float*)d_out, 1.0f / (float)B);
}

// Round 7
// 466.510 us; speedup vs baseline: 1.1195x; 1.0519x over previous
//
#include <hip/hip_runtime.h>

#define D 128
#define NB 512   // bucket slots per domain (bucket = node >> 8)
#define BSLACK 4160   // per-bucket CSR slack: 256*16 pad + 15 align + 48 sentinels (min gap 49)
#define CHUNK 8       // consecutive nodes streamed per wave (must divide 256)
#define LDSCAP 12288  // per-bucket LDS staging capacity (ints); fallback if exceeded

typedef __attribute__((ext_vector_type(8))) short bf16x8;
typedef __attribute__((ext_vector_type(4))) float f32x4;
typedef __attribute__((ext_vector_type(2))) float f32x2;
typedef __attribute__((ext_vector_type(4))) int i32x4;

static __device__ inline unsigned pack_bf16x2(float a, float b) {
    unsigned ua = __float_as_uint(a);
    unsigned ub = __float_as_uint(b);
    ua += 0x7fffu + ((ua >> 16) & 1u);
    ub += 0x7fffu + ((ub >> 16) & 1u);
    return (ua >> 16) | (ub & 0xffff0000u);
}

// ---- bucket histogram (LDS only) ----
__global__ __launch_bounds__(256) void bh_k(const int* __restrict__ dst_s,
                                            const int* __restrict__ dst_t,
                                            int* __restrict__ bcnt, int E) {
    int d = blockIdx.y;
    const int* dst = d ? dst_t : dst_s;
    __shared__ int h[NB];
    for (int i = threadIdx.x; i < NB; i += 256) h[i] = 0;
    __syncthreads();
    int stride = gridDim.x * 256;
    for (int e = blockIdx.x * 256 + threadIdx.x; e < E; e += stride)
        atomicAdd(&h[dst[e] >> 8], 1);
    __syncthreads();
    for (int i = threadIdx.x; i < NB; i += 256)
        if (h[i]) atomicAdd(&bcnt[d * NB + i], h[i]);
}

// ---- exclusive scan of 1024 bucket counts; packW fused (idle-thread work) ----
__global__ __launch_bounds__(1024) void scanB_k(const int* __restrict__ bcnt,
                                                int* __restrict__ bbase,
                                                int* __restrict__ cursor,
                                                const float* __restrict__ W1,
                                                const float* __restrict__ W2,
                                                unsigned short* __restrict__ wp1,
                                                unsigned short* __restrict__ wp2) {
    __shared__ int sh[1024];
    int t = threadIdx.x;
    int v = bcnt[t];
    sh[t] = v;
    __syncthreads();
    for (int o = 1; o < 1024; o <<= 1) {
        int x = (t >= o) ? sh[t - o] : 0;
        __syncthreads();
        sh[t] += x;
        __syncthreads();
    }
    int ex = sh[t] - v;
    bbase[t] = ex; cursor[t] = ex;
    if (t == 1023) bbase[1024] = sh[1023];
    // fused packW (independent of scan results)
    #pragma unroll
    for (int m = 0; m < 2; ++m) {
        const float* W = m ? W2 : W1;
        unsigned short* wp = m ? wp2 : wp1;
        for (int idx = t; idx < 2048; idx += 1024) {
            int f = idx >> 6, lane = idx & 63;
            int tt = f >> 2, c = f & 3;
            int q = lane >> 4, nn = lane & 15;
            #pragma unroll
            for (int j = 0; j < 8; ++j) {
                unsigned u = __float_as_uint(W[(c * 32 + q * 8 + j) * 128 + tt * 16 + nn]);
                u += 0x7fffu + ((u >> 16) & 1u);
                wp[idx * 8 + j] = (unsigned short)(u >> 16);
            }
        }
    }
}

// ---- bin edges into bucket regions: src | (dst&255)<<24 ----
__global__ __launch_bounds__(256) void bin_k(const int* __restrict__ src_s,
                                             const int* __restrict__ dst_s,
                                             const int* __restrict__ src_t,
                                             const int* __restrict__ dst_t,
                                             int* __restrict__ cursor,
                                             unsigned* __restrict__ pairs, int E) {
    int d = blockIdx.y;
    const int* src = d ? src_t : src_s;
    const int* dst = d ? dst_t : dst_s;
    int* cur = cursor + d * NB;
    __shared__ int h[NB];
    __shared__ int gb[NB];
    int t0 = blockIdx.x * 2048;
    if (t0 >= E) return;
    for (int i = threadIdx.x; i < NB; i += 256) h[i] = 0;
    __syncthreads();
    int rank[8]; unsigned pk[8]; short bk[8];
    #pragma unroll
    for (int j = 0; j < 8; ++j) {
        int e = t0 + j * 256 + threadIdx.x;
        if (e < E) {
            int dd = dst[e], s = src[e];
            bk[j] = (short)(dd >> 8);
            pk[j] = (unsigned)s | ((unsigned)(dd & 255) << 24);
            rank[j] = atomicAdd(&h[dd >> 8], 1);
        } else bk[j] = -1;
    }
    __syncthreads();
    for (int i = threadIdx.x; i < NB; i += 256)
        gb[i] = h[i] ? atomicAdd(&cur[i], h[i]) : 0;
    __syncthreads();
    #pragma unroll
    for (int j = 0; j < 8; ++j)
        if (bk[j] >= 0) pairs[gb[bk[j]] + rank[j]] = pk[j];
}

// ---- per-bucket: LDS node hist -> nspan/dinv; build whole CSR region in LDS,
// flush coalesced. Fallback to direct global scatter if region > LDSCAP.
__global__ __launch_bounds__(256) void csrb_k(const unsigned* __restrict__ pairs,
                                              const int* __restrict__ bbase,
                                              int2* __restrict__ nspan,
                                              float* __restrict__ dinv,
                                              int* __restrict__ csr, int N) {
    int d = blockIdx.y, bx = blockIdx.x, t = threadIdx.x;
    int g = d * NB + bx;
    int e0 = bbase[g], e1 = bbase[g + 1];
    int cbase = ((e0 + 15) & ~15) + g * BSLACK;
    float* dv = dinv + (size_t)d * (N + 1);
    int2* ns = nspan + (size_t)d * N;
    __shared__ int lh[256];
    __shared__ int lex[256];
    __shared__ int lc[256];
    __shared__ int ls[LDSCAP];
    lh[t] = 0; lc[t] = 0;
    __syncthreads();
    for (int e = e0 + t; e < e1; e += 256)
        atomicAdd(&lh[pairs[e] >> 24], 1);
    __syncthreads();
    int node = (bx << 8) + t;
    bool valid = node < N;
    int deg = lh[t];
    int pdeg = valid ? (((deg + 16) >> 4) << 4) : 0;   // pad16(deg + self)
    lex[t] = pdeg;
    __syncthreads();
    for (int o = 1; o < 256; o <<= 1) {
        int x = (t >= o) ? lex[t - o] : 0;
        __syncthreads();
        lex[t] += x;
        __syncthreads();
    }
    int tot = lex[255];                   // uniform; region entry count
    int start_local = lex[t] - pdeg;
    int start = cbase + start_local;
    if (valid) {
        ns[node] = make_int2(start, start + pdeg);
        dv[node] = rsqrtf((float)(deg + 1));
    }
    bool fits = (tot + 48) <= LDSCAP;     // uniform
    __syncthreads();                      // protect lex[255] read before overwrite
    lex[t] = fits ? start_local : start;  // scatter base (local or global)
    __syncthreads();
    if (fits) {
        for (int e = e0 + t; e < e1; e += 256) {
            unsigned p = pairs[e];
            int dn = p >> 24;
            int r = atomicAdd(&lc[dn], 1);
            ls[lex[dn] + r] = (int)(p & 0xffffffu);
        }
        __syncthreads();
        if (valid) {
            int b = lex[t];
            ls[b + deg] = node;                              // self term
            for (int k = deg + 1; k < pdeg; ++k) ls[b + k] = N;  // pad sentinels
        }
        if (t < 48) ls[tot + t] = N;                         // tail sentinels
        __syncthreads();
        int tt = tot + 48;
        for (int i = t; i < tt; i += 256) csr[cbase + i] = ls[i];
    } else {
        for (int e = e0 + t; e < e1; e += 256) {
            unsigned p = pairs[e];
            int dn = p >> 24;
            int r = atomicAdd(&lc[dn], 1);
            csr[lex[dn] + r] = (int)(p & 0xffffffu);
        }
        __syncthreads();
        if (valid) {
            int b = lex[t];
            csr[b + deg] = node;
            for (int k = deg + 1; k < pdeg; ++k) csr[b + k] = N;
        }
        if (t == 255) {
            int bend = start + pdeg;
            for (int i = 0; i < 48; ++i) csr[bend + i] = N;
        }
    }
    if (bx == 0 && t == 0) dv[N] = 0.f;                 // sentinel row scale
}

// ================= MFMA GEMM =================
// hbuf8 row r (fp8) = fp8( dinv[r] * (x[r] @ W) )  -- pre-scaled; row N = zeros (dinv=0)
__global__ __launch_bounds__(256) void gemm_mfma(const void* __restrict__ xs,
                                                 const void* __restrict__ xt,
                                                 const unsigned short* __restrict__ wp,
                                                 unsigned* __restrict__ hb,
                                                 const float* __restrict__ dinv,
                                                 int N, int in_bf16) {
    int d = blockIdx.y;
    const void* xin = d ? xt : xs;
    unsigned* out = hb + (size_t)d * (N + 1) * 32;
    const float* dv = dinv + (size_t)d * (N + 1);
    __shared__ float cs[64 * 132];
    int tid = threadIdx.x;
    int wave = tid >> 6, lane = tid & 63;
    int quad = lane >> 4, nn = lane & 15;
    long long blockbase = (long long)blockIdx.x * 64;
    long long ar = blockbase + wave * 16 + nn;
    if (ar > N - 1) ar = N - 1;          // inputs have N rows

    bf16x8 a[4];
    if (in_bf16) {
        const uint4* xr = (const uint4*)((const unsigned short*)xin + ar * 128);
        #pragma unroll
        for (int c = 0; c < 4; ++c) {
            union { uint4 u; bf16x8 v; } cv;
            cv.u = xr[c * 4 + quad];
            a[c] = cv.v;
        }
    } else {
        const float4* xr = (const float4*)((const float*)xin + ar * 128);
        #pragma unroll
        for (int c = 0; c < 4; ++c) {
            float4 lo = xr[c * 8 + quad * 2];
            float4 hi = xr[c * 8 + quad * 2 + 1];
            union { bf16x8 v; unsigned u[4]; } au;
            au.u[0] = pack_bf16x2(lo.x, lo.y);
            au.u[1] = pack_bf16x2(lo.z, lo.w);
            au.u[2] = pack_bf16x2(hi.x, hi.y);
            au.u[3] = pack_bf16x2(hi.z, hi.w);
            a[c] = au.v;
        }
    }

    f32x4 acc[8];
    #pragma unroll
    for (int t = 0; t < 8; ++t) acc[t] = (f32x4){0.f, 0.f, 0.f, 0.f};
    const bf16x8* wf = (const bf16x8*)wp;
    #pragma unroll
    for (int t = 0; t < 8; ++t) {
        #pragma unroll
        for (int c = 0; c < 4; ++c) {
            bf16x8 b = wf[(t * 4 + c) * 64 + lane];
            acc[t] = __builtin_amdgcn_mfma_f32_16x16x32_bf16(a[c], b, acc[t], 0, 0, 0);
        }
    }

    #pragma unroll
    for (int t = 0; t < 8; ++t) {
        #pragma unroll
        for (int r = 0; r < 4; ++r)
            cs[(wave * 16 + quad * 4 + r) * 132 + t * 16 + nn] = acc[t][r];
    }
    __syncthreads();

    #pragma unroll
    for (int i = 0; i < 8; ++i) {
        int idx = tid + i * 256;
        int r = idx >> 5, c4 = idx & 31;
        long long row = blockbase + r;
        if (row <= N) {
            float s = dv[row];
            const float4 v = *(const float4*)&cs[r * 132 + c4 * 4];
            int pk = __builtin_amdgcn_cvt_pk_fp8_f32(v.x * s, v.y * s, 0, false);
            pk = __builtin_amdgcn_cvt_pk_fp8_f32(v.z * s, v.w * s, pk, true);
            out[row * 32 + c4] = (unsigned)pk;
        }
    }
}

// ---- streaming agg (R3-proven structure): one wave owns CHUNK consecutive
// nodes; spans within a bucket are contiguous/16-aligned so the wave streams
// the CSR region with a loop-carried 1-window-ahead ping-pong (uA/uB).
#define NTLD(p) __builtin_nontemporal_load((const i32x4*)(p))

#define AGG_GATHER(u, q0, q1)                                                \
        u[0] = hsl[((unsigned)(q0).x) << 5];                                 \
        u[1] = hsl[((unsigned)(q0).y) << 5];                                 \
        u[2] = hsl[((unsigned)(q0).z) << 5];                                 \
        u[3] = hsl[((unsigned)(q0).w) << 5];                                 \
        u[4] = hsl[((unsigned)(q1).x) << 5];                                 \
        u[5] = hsl[((unsigned)(q1).y) << 5];                                 \
        u[6] = hsl[((unsigned)(q1).z) << 5];                                 \
        u[7] = hsl[((unsigned)(q1).w) << 5];

#define AGG_CONSUME(u)                                                       \
        { f32x2 lo, hi;                                                      \
          lo = __builtin_amdgcn_cvt_pk_f32_fp8((int)u[0], false);            \
          hi = __builtin_amdgcn_cvt_pk_f32_fp8((int)u[0], true);             \
          s01 += lo; s23 += hi;                                              \
          lo = __builtin_amdgcn_cvt_pk_f32_fp8((int)u[1], false);            \
          hi = __builtin_amdgcn_cvt_pk_f32_fp8((int)u[1], true);             \
          s01 += lo; s23 += hi;                                              \
          lo = __builtin_amdgcn_cvt_pk_f32_fp8((int)u[2], false);            \
          hi = __builtin_amdgcn_cvt_pk_f32_fp8((int)u[2], true);             \
          s01 += lo; s23 += hi;                                              \
          lo = __builtin_amdgcn_cvt_pk_f32_fp8((int)u[3], false);            \
          hi = __builtin_amdgcn_cvt_pk_f32_fp8((int)u[3], true);             \
          s01 += lo; s23 += hi;                                              \
          lo = __builtin_amdgcn_cvt_pk_f32_fp8((int)u[4], false);            \
          hi = __builtin_amdgcn_cvt_pk_f32_fp8((int)u[4], true);             \
          s01 += lo; s23 += hi;                                              \
          lo = __builtin_amdgcn_cvt_pk_f32_fp8((int)u[5], false);            \
          hi = __builtin_amdgcn_cvt_pk_f32_fp8((int)u[5], true);             \
          s01 += lo; s23 += hi;                                              \
          lo = __builtin_amdgcn_cvt_pk_f32_fp8((int)u[6], false);            \
          hi = __builtin_amdgcn_cvt_pk_f32_fp8((int)u[6], true);             \
          s01 += lo; s23 += hi;                                              \
          lo = __builtin_amdgcn_cvt_pk_f32_fp8((int)u[7], false);            \
          hi = __builtin_amdgcn_cvt_pk_f32_fp8((int)u[7], true);             \
          s01 += lo; s23 += hi; }

#define BOUND                                                                \
        if (en >= end) {                                                     \
            finalize(k);                                                     \
            if (++k >= cnt) break;                                           \
            end = __shfl(myns.y, k);                                         \
            s01 = (f32x2){0.f, 0.f};                                         \
            s23 = (f32x2){0.f, 0.f};                                         \
        }                                                                    \
        e = en;

#define AGG_PIPE_LOOP                                                        \
    i32x4 c0 = NTLD(cp + e), c1 = NTLD(cp + e + 4);                          \
    unsigned uA[8], uB[8];                                                   \
    AGG_GATHER(uA, c0, c1)                                                   \
    c0 = NTLD(cp + e + 16); c1 = NTLD(cp + e + 20);                          \
    for (;;) {                                                               \
        int en = e + 16;                                                     \
        AGG_GATHER(uB, c0, c1)                                               \
        c0 = NTLD(cp + en + 16); c1 = NTLD(cp + en + 20);                    \
        AGG_CONSUME(uA)                                                      \
        BOUND                                                                \
        en = e + 16;                                                         \
        AGG_GATHER(uA, c0, c1)                                               \
        c0 = NTLD(cp + en + 16); c1 = NTLD(cp + en + 20);                    \
        AGG_CONSUME(uB)                                                      \
        BOUND                                                                \
    }

// ---- agg layer 1: sum of pre-scaled fp8 rows over pad16 list; bf16+relu out ----
__global__ __launch_bounds__(256) void agg1_k(const unsigned* __restrict__ hb,
                                              const float* __restrict__ dinv,
                                              const int2* __restrict__ nspan,
                                              const int* __restrict__ csr,
                                              const float* __restrict__ bias,
                                              uint2* __restrict__ out, int N) {
    int d = blockIdx.y;
    const unsigned* hs = hb + (size_t)d * (N + 1) * 32;
    const float* dv = dinv + (size_t)d * (N + 1);
    const int2* ns = nspan + (size_t)d * N;
    uint2* outp = out + (size_t)d * N * 32;
    int wave = threadIdx.x >> 6, lane = threadIdx.x & 63;
    int node0 = (blockIdx.x * 4 + wave) * CHUNK;
    if (node0 >= N) return;
    int cnt = min(CHUNK, N - node0);
    int half = lane >> 5, li = lane & 31;
    int lc = lane & (CHUNK - 1);
    int2 myns = make_int2(0, 0);
    float mydv = 0.f;
    if (lc < cnt) { myns = ns[node0 + lc]; mydv = dv[node0 + lc]; }
    float4 b4 = ((const float4*)bias)[li];
    const unsigned* hsl = hs + li;
    const int* cp = csr + 8 * half;

    f32x2 s01 = (f32x2){0.f, 0.f};
    f32x2 s23 = (f32x2){0.f, 0.f};

    auto finalize = [&](int kk) {
        float a0f = s01[0], a1f = s01[1], a2f = s23[0], a3f = s23[1];
        a0f += __shfl_xor(a0f, 32);
        a1f += __shfl_xor(a1f, 32);
        a2f += __shfl_xor(a2f, 32);
        a3f += __shfl_xor(a3f, 32);
        float dik = __shfl(mydv, kk);
        float o0 = fmaxf(fmaf(dik, a0f, b4.x), 0.f);
        float o1 = fmaxf(fmaf(dik, a1f, b4.y), 0.f);
        float o2 = fmaxf(fmaf(dik, a2f, b4.z), 0.f);
        float o3 = fmaxf(fmaf(dik, a3f, b4.w), 0.f);
        if (half == 0)
            outp[(size_t)(node0 + kk) * 32 + li] =
                make_uint2(pack_bf16x2(o0, o1), pack_bf16x2(o2, o3));
    };

    int k = 0;
    int e = __shfl(myns.x, 0);
    int end = __shfl(myns.y, 0);
    AGG_PIPE_LOOP
}

// ---- agg layer 2 fused with per-node loss dots ----
__global__ __launch_bounds__(256) void agg2_k(const unsigned* __restrict__ hb,
                                              const float* __restrict__ dinv,
                                              const int2* __restrict__ nspan,
                                              const int* __restrict__ csr,
                                              const float* __restrict__ bias,
                                              const float* __restrict__ clsW,
                                              const float* __restrict__ duW,
                                              const float* __restrict__ diW,
                                              const int* __restrict__ nus,
                                              const int* __restrict__ nut,
                                              float2* __restrict__ nodeDots, int N) {
    int d = blockIdx.y;
    const unsigned* hs = hb + (size_t)d * (N + 1) * 32;
    const float* dv = dinv + (size_t)d * (N + 1);
    const int2* ns = nspan + (size_t)d * N;
    float2* nd = nodeDots + (size_t)d * N;
    int nu = d ? nut[0] : nus[0];
    int wave = threadIdx.x >> 6, lane = threadIdx.x & 63;
    int node0 = (blockIdx.x * 4 + wave) * CHUNK;
    if (node0 >= N) return;
    int cnt = min(CHUNK, N - node0);
    int half = lane >> 5, li = lane & 31;
    int lc = lane & (CHUNK - 1);
    int2 myns = make_int2(0, 0);
    float mydv = 0.f;
    if (lc < cnt) { myns = ns[node0 + lc]; mydv = dv[node0 + lc]; }
    float4 b4 = ((const float4*)bias)[li];
    float4 wA0 = ((const float4*)clsW)[li];
    float4 wA1 = ((const float4*)clsW)[32 + li];
    float4 wB0 = ((const float4*)duW)[li];
    float4 wB1 = ((const float4*)diW)[li];
    const unsigned* hsl = hs + li;
    const int* cp = csr + 8 * half;

    f32x2 s01 = (f32x2){0.f, 0.f};
    f32x2 s23 = (f32x2){0.f, 0.f};

    auto finalize = [&](int kk) {
        float a0f = s01[0], a1f = s01[1], a2f = s23[0], a3f = s23[1];
        a0f += __shfl_xor(a0f, 32);
        a1f += __shfl_xor(a1f, 32);
        a2f += __shfl_xor(a2f, 32);
        a3f += __shfl_xor(a3f, 32);
        float dik = __shfl(mydv, kk);
        float o0 = fmaf(dik, a0f, b4.x);
        float o1 = fmaf(dik, a1f, b4.y);
        float o2 = fmaf(dik, a2f, b4.z);
        float o3 = fmaf(dik, a3f, b4.w);
        int nodek = node0 + kk;
        int sel = (nodek >= nu) ? 1 : 0;
        float4 wA = sel ? wA1 : wA0;
        float4 wB = sel ? wB1 : wB0;
        float p = o0 * wA.x + o1 * wA.y + o2 * wA.z + o3 * wA.w;
        float q = o0 * wB.x + o1 * wB.y + o2 * wB.z + o3 * wB.w;
        #pragma unroll
        for (int o = 16; o > 0; o >>= 1) {
            p += __shfl_xor(p, o);
            q += __shfl_xor(q, o);
        }
        if (lane == 0) nd[nodek] = make_float2(p, q);
    };

    int k = 0;
    int e = __shfl(myns.x, 0);
    int end = __shfl(myns.y, 0);
    AGG_PIPE_LOOP
}

// ---- pair loss ----
__global__ __launch_bounds__(256) void loss_k(const float2* __restrict__ nodeDots,
                                              const int* __restrict__ us, const int* __restrict__ is_,
                                              const int* __restrict__ ls,
                                              const int* __restrict__ ut, const int* __restrict__ it,
                                              const int* __restrict__ lt,
                                              const float* __restrict__ clsb,
                                              const float* __restrict__ dub,
                                              const float* __restrict__ dib,
                                              const int* __restrict__ nus,
                                              const int* __restrict__ nut,
                                              float* __restrict__ accum, int Bn, int N) {
    int d = blockIdx.y;
    const float2* nd = nodeDots + (size_t)d * N;
    const int* users = d ? ut : us;
    const int* items = d ? it : is_;
    const int* labels = d ? lt : ls;
    int nu = d ? nut[0] : nus[0];
    float* acc = accum + 3 * d;
    int k = blockIdx.x * 256 + threadIdx.x;
    float bce = 0.f, cu = 0.f, ci = 0.f;
    if (k < Bn) {
        int u = users[k];
        int t = items[k] + nu;
        float2 ud = nd[u];
        float2 id = nd[t];
        float z = ud.x + id.x + clsb[0];
        float y = (float)labels[k];
        float sp = fmaxf(z, 0.f) + log1pf(expf(-fabsf(z)));
        bce = sp - y * z;
        cu = 1.f / (1.f + expf(-(ud.y + dub[0])));
        ci = 1.f / (1.f + expf(-(id.y + dib[0])));
    }
    #pragma unroll
    for (int o = 32; o > 0; o >>= 1) {
        bce += __shfl_xor(bce, o);
        cu += __shfl_xor(cu, o);
        ci += __shfl_xor(ci, o);
    }
    __shared__ float sh[12];
    int lane = threadIdx.x & 63, wave = threadIdx.x >> 6;
    if (lane == 0) { sh[wave * 3 + 0] = bce; sh[wave * 3 + 1] = cu; sh[wave * 3 + 2] = ci; }
    __syncthreads();
    if (threadIdx.x < 3) {
        float v = sh[threadIdx.x] + sh[3 + threadIdx.x] + sh[6 + threadIdx.x] + sh[9 + threadIdx.x];
        atomicAdd(&acc[threadIdx.x], v);
    }
}

__global__ void finalize_k(const float* __restrict__ accum, float* __restrict__ out, float invB) {
    if (threadIdx.x == 0 && blockIdx.x == 0) {
        float clf = (accum[0] + accum[3]) * invB;
        float dom = fabsf((accum[1] - accum[4]) * invB) + fabsf((accum[2] - accum[5]) * invB);
        out[0] = clf + dom;
    }
}

extern "C" void kernel_launch(void* const* d_in, const int* in_sizes, int n_in,
                              void* d_out, int out_size, void* d_ws, size_t ws_size,
                              hipStream_t stream) {
    const float* feats_s = (const float*)d_in[0];
    const float* feats_t = (const float*)d_in[1];
    const float* W1   = (const float*)d_in[2];
    const float* b1   = (const float*)d_in[3];
    const float* W2   = (const float*)d_in[4];
    const float* b2   = (const float*)d_in[5];
    const float* clsW = (const float*)d_in[6];
    const float* clsb = (const float*)d_in[7];
    const float* duW  = (const float*)d_in[8];
    const float* dub  = (const float*)d_in[9];
    const float* diW  = (const float*)d_in[10];
    const float* dib  = (const float*)d_in[11];

    int N = in_sizes[0] / D;
    int E = in_sizes[12];
    int B = in_sizes[16];
    int nb = (N + 255) >> 8;          // real buckets per domain (<= NB)

    char* ws = (char*)d_ws;
    size_t off = 0;
    auto alloc = [&](size_t bytes) -> void* {
        void* p = ws + off;
        off += (bytes + 255) & ~(size_t)255;
        return p;
    };
    int*      bcnt   = (int*)  alloc(2 * NB * 4);
    int*      bbase  = (int*)  alloc((2 * NB + 1) * 4);
    int*      cursor = (int*)  alloc(2 * NB * 4);
    float*    dinv   = (float*)alloc((size_t)2 * (N + 1) * 4);
    int2*     nspan  = (int2*) alloc((size_t)2 * N * 8);
    unsigned* pairs  = (unsigned*)alloc((size_t)2 * E * 4);
    int*      csr    = (int*)  alloc(((size_t)2 * E + 2 * NB * BSLACK + 256) * 4);
    unsigned* hbuf8  = (unsigned*)alloc((size_t)2 * (N + 1) * 128);   // fp8 pre-scaled rows
    unsigned* abuf   = (unsigned*)alloc((size_t)2 * N * 256);         // bf16 agg1 rows
    float2*   nodeDots = (float2*)alloc((size_t)2 * N * 8);
    unsigned short* wp1 = (unsigned short*)alloc(16384 * 2);
    unsigned short* wp2 = (unsigned short*)alloc(16384 * 2);
    float*    accum  = (float*)alloc(128);

    hipMemsetAsync(accum, 0, 6 * sizeof(float), stream);
    hipMemsetAsync(bcnt, 0, 2 * NB * 4, stream);

    const int* esrc_s = (const int*)d_in[12];
    const int* edst_s = (const int*)d_in[13];
    const int* esrc_t = (const int*)d_in[14];
    const int* edst_t = (const int*)d_in[15];
    const int* user_s = (const int*)d_in[16];
    const int* item_s = (const int*)d_in[17];
    const int* lab_s  = (const int*)d_in[18];
    const int* user_t = (const int*)d_in[19];
    const int* item_t = (const int*)d_in[20];
    const int* lab_t  = (const int*)d_in[21];
    const int* nup_s  = (const int*)d_in[22];
    const int* nup_t  = (const int*)d_in[23];

    bh_k<<<dim3(512, 2), 256, 0, stream>>>(edst_s, edst_t, bcnt, E);
    scanB_k<<<1, 1024, 0, stream>>>(bcnt, bbase, cursor, W1, W2, wp1, wp2);
    bin_k<<<dim3((E + 2047) / 2048, 2), 256, 0, stream>>>(esrc_s, edst_s, esrc_t, edst_t,
                                                          cursor, pairs, E);
    csrb_k<<<dim3(nb, 2), 256, 0, stream>>>(pairs, bbase, nspan, dinv, csr, N);

    int ngb = (N + 64) / 64;   // covers rows 0..N (incl. sentinel row N)
    int nchunk = (N + CHUNK - 1) / CHUNK;
    gemm_mfma<<<dim3(ngb, 2), 256, 0, stream>>>(feats_s, feats_t, wp1, hbuf8, dinv, N, 0);
    agg1_k<<<dim3((nchunk + 3) / 4, 2), 256, 0, stream>>>(hbuf8, dinv, nspan, csr, b1,
                                                          (uint2*)abuf, N);
    gemm_mfma<<<dim3(ngb, 2), 256, 0, stream>>>(abuf, abuf + (size_t)N * 64, wp2,
                                                hbuf8, dinv, N, 1);
    agg2_k<<<dim3((nchunk + 3) / 4, 2), 256, 0, stream>>>(hbuf8, dinv, nspan, csr, b2,
                                                          clsW, duW, diW, nup_s, nup_t,
                                                          nodeDots, N);
    loss_k<<<dim3((B + 255) / 256, 2), 256, 0, stream>>>(nodeDots,
                                                         user_s, item_s, lab_s,
                                                         user_t, item_t, lab_t,
                                                         clsb, dub, dib, nup_s, nup_t,
                                                         accum, B, N);
    finalize_k<<<1, 64, 0, stream>>>(accum, (float*)d_out, 1.0f / (float)B);
}